// Round 5
// baseline (2539.205 us; speedup 1.0000x reference)
//
#include <hip/hip_runtime.h>

typedef unsigned short u16;
typedef unsigned int   u32;

#define DIMC 192
#define NWIN 343
#define LTOK 21952
#define ROWSZ 43904            // B * L rows
#define TOTE 8429568           // ROWSZ * DIMC
#define QSCALE 0.17677669529663689f
#define EPSF 1e-5f
#define KSTR 352               // Ks transposed stride (bf16 elems)
#define VSTR 356               // Vs transposed stride (bf16 elems), 8B-aligned rows

__device__ __forceinline__ float bu(u16 v){ union{u32 u; float f;} x; x.u = ((u32)v)<<16; return x.f; }
__device__ __forceinline__ float lo16(u32 p){ union{u32 u; float f;} x; x.u = p<<16; return x.f; }
__device__ __forceinline__ float hi16(u32 p){ union{u32 u; float f;} x; x.u = p & 0xffff0000u; return x.f; }
__device__ __forceinline__ u16 fb(float f){
  union{float ff; u32 u;} x; x.ff = f;
  u32 r = (x.u + 0x7fffu + ((x.u>>16)&1u)) >> 16;
  return (u16)r;
}
__device__ __forceinline__ float gelu_f(float x){ return 0.5f*x*(1.0f + erff(x*0.70710678118654752f)); }

// windowed-row -> (batch, token) bijection (shift -3 + partition; same map used
// for the reverse scatter).
__device__ __forceinline__ void row_to_token(int row, int& b, int& l){
  int bw = row / NWIN, n = row % NWIN;
  b = bw >> 6; int wi = bw & 63;
  int sd = (wi>>4)*7      + n/49;
  int sh = ((wi>>2)&3)*7  + (n/7)%7;
  int sw = (wi&3)*7       + n%7;
  int d = sd+3; if(d>=28) d-=28;
  int h = sh+3; if(h>=28) h-=28;
  int w = sw+3; if(w>=28) w-=28;
  l = d*784 + h*28 + w;
}

// ---------------- LN1: f32 x -> bf16 windowed ----------------
__global__ __launch_bounds__(256) void ln_win(const float* __restrict__ x, const float* __restrict__ g,
                                              const float* __restrict__ bb, u16* __restrict__ out){
  int row  = blockIdx.x*4 + (threadIdx.x>>6);
  int lane = threadIdx.x & 63;
  int b, l; row_to_token(row, b, l);
  const float* p = x + ((long)b*LTOK + l)*DIMC;
  float v0 = p[lane], v1 = p[lane+64], v2 = p[lane+128];
  float s = v0+v1+v2;
  #pragma unroll
  for(int m=1;m<64;m<<=1) s += __shfl_xor(s,m);
  float mean = s*(1.f/192.f);
  float d0=v0-mean, d1=v1-mean, d2=v2-mean;
  float q = d0*d0+d1*d1+d2*d2;
  #pragma unroll
  for(int m=1;m<64;m<<=1) q += __shfl_xor(q,m);
  float rstd = rsqrtf(q*(1.f/192.f)+EPSF);
  u16* o = out + (long)row*DIMC;
  o[lane]     = fb(d0*rstd*g[lane]     + bb[lane]);
  o[lane+64]  = fb(d1*rstd*g[lane+64]  + bb[lane+64]);
  o[lane+128] = fb(d2*rstd*g[lane+128] + bb[lane+128]);
}

// ---------------- LN2: bf16 x1 -> bf16 xm ----------------
__global__ __launch_bounds__(256) void ln_plain(const u16* __restrict__ in, const float* __restrict__ g,
                                                const float* __restrict__ bb, u16* __restrict__ out){
  int row  = blockIdx.x*4 + (threadIdx.x>>6);
  int lane = threadIdx.x & 63;
  const u16* p = in + (long)row*DIMC;
  float v0 = bu(p[lane]), v1 = bu(p[lane+64]), v2 = bu(p[lane+128]);
  float s = v0+v1+v2;
  #pragma unroll
  for(int m=1;m<64;m<<=1) s += __shfl_xor(s,m);
  float mean = s*(1.f/192.f);
  float d0=v0-mean, d1=v1-mean, d2=v2-mean;
  float q = d0*d0+d1*d1+d2*d2;
  #pragma unroll
  for(int m=1;m<64;m<<=1) q += __shfl_xor(q,m);
  float rstd = rsqrtf(q*(1.f/192.f)+EPSF);
  u16* o = out + (long)row*DIMC;
  o[lane]     = fb(d0*rstd*g[lane]     + bb[lane]);
  o[lane+64]  = fb(d1*rstd*g[lane+64]  + bb[lane+64]);
  o[lane+128] = fb(d2*rstd*g[lane+128] + bb[lane+128]);
}

// ---------------- generic 16-row x (192 -> CJ*192) GEMM, bf16 A, f32 W ----------------
// EPI: 0/1 = bf16 out + bias ; 2 = proj: bias + window-reverse + residual(f32 x) -> bf16 x1
// WT:  0 = W (k, c) row-major ; 1 = W (c, k) row-major (pointwise conv kernels)
template<int CJ, int EPI, int WT>
__global__ __launch_bounds__(192) void gemm16(const u16* __restrict__ A, const float* __restrict__ W,
                                              const float* __restrict__ bias, u16* __restrict__ out,
                                              const float* __restrict__ resid){
  constexpr int NC = CJ*192;
  __shared__ float a_s[16*192];
  const int tid = threadIdx.x;
  const long row0 = (long)blockIdx.x*16;
  for(int idx=tid; idx<16*192; idx+=192) a_s[idx] = bu(A[row0*192 + idx]);
  __syncthreads();

  float acc[CJ][16];
  #pragma unroll
  for(int cj=0;cj<CJ;cj++)
    #pragma unroll
    for(int r=0;r<16;r++) acc[cj][r]=0.f;

  for(int k4=0;k4<192;k4+=4){
    float4 av[16];
    #pragma unroll
    for(int r=0;r<16;r++) av[r] = *(const float4*)&a_s[r*192+k4];
    #pragma unroll
    for(int cj=0;cj<CJ;cj++){
      const int c = cj*192 + tid;
      float w0,w1,w2,w3;
      if constexpr(WT==1){
        float4 t = *(const float4*)&W[(long)c*192 + k4];
        w0=t.x; w1=t.y; w2=t.z; w3=t.w;
      } else {
        w0 = W[(long)(k4+0)*NC + c];
        w1 = W[(long)(k4+1)*NC + c];
        w2 = W[(long)(k4+2)*NC + c];
        w3 = W[(long)(k4+3)*NC + c];
      }
      #pragma unroll
      for(int r=0;r<16;r++){
        float a = acc[cj][r];
        a = fmaf(av[r].x, w0, a);
        a = fmaf(av[r].y, w1, a);
        a = fmaf(av[r].z, w2, a);
        a = fmaf(av[r].w, w3, a);
        acc[cj][r] = a;
      }
    }
  }

  if constexpr(EPI==2){
    float bv = bias[tid];
    #pragma unroll
    for(int r=0;r<16;r++){
      int b, l; row_to_token((int)(row0+r), b, l);
      long li = ((long)b*LTOK + l)*DIMC + tid;
      out[li] = fb(acc[0][r] + bv + resid[li]);
    }
  } else {
    #pragma unroll
    for(int cj=0;cj<CJ;cj++){
      const int c = cj*192 + tid;
      float bv = bias[c];
      #pragma unroll
      for(int r=0;r<16;r++) out[(row0+r)*NC + c] = fb(acc[cj][r] + bv);
    }
  }
}

// ---------------- attention: one block per (window-batch, head) ----------------
__global__ __launch_bounds__(256) void attn_kernel(const u16* __restrict__ qkv, const float* __restrict__ rpb,
                                                   const float* __restrict__ mask, u16* __restrict__ out){
  __shared__ u16 Ks[32*KSTR];
  __shared__ u16 Vs[32*VSTR];
  __shared__ float ps[8][344];
  __shared__ float qs[8][32];

  const int tid = threadIdx.x;
  const int bw = blockIdx.x / 6, hh = blockIdx.x % 6;
  const int wi = bw & 63;
  const long rowbase = (long)bw*NWIN;

  for(int idx=tid; idx<NWIN*32; idx+=256){
    int j = idx >> 5, d = idx & 31;
    long p = (rowbase + j)*576 + hh*32 + d;
    Ks[d*KSTR + j] = qkv[p + 192];
    Vs[d*VSTR + j] = qkv[p + 384];
  }
  if(tid < 32){ Ks[tid*KSTR + 343] = 0; Vs[tid*VSTR + 343] = 0; }
  if(tid < 8) ps[tid][343] = 0.f;
  __syncthreads();

  const int wv   = tid >> 6;
  const int lane = tid & 63;
  const int half = lane >> 5;
  const int l    = lane & 31;
  const int g    = wv*2 + half;

  for(int it=0; it<43; ++it){
    int i0 = it*8 + g;
    bool rowok = i0 < NWIN;
    int i = rowok ? i0 : (NWIN-1);

    qs[g][l] = bu(qkv[(rowbase + i)*576 + hh*32 + l]) * QSCALE;
    float qr[32];
    {
      const float4* qp = (const float4*)qs[g];
      #pragma unroll
      for(int c4=0;c4<8;c4++){
        float4 t4 = qp[c4];
        qr[c4*4+0]=t4.x; qr[c4*4+1]=t4.y; qr[c4*4+2]=t4.z; qr[c4*4+3]=t4.w;
      }
    }

    const int iz = i/49, iy = (i/7)%7, ix = i%7;
    const long maskrow = ((long)wi*NWIN + i)*NWIN;

    float sc[12];
    float mx = -1e30f;
    #pragma unroll
    for(int t=0;t<6;t++){
      int j0 = 2*l + 64*t;
      float s0 = -1e30f, s1 = -1e30f;
      if(j0 < NWIN){
        float a0=0.f, a1=0.f;
        const u16* kcol = Ks + j0;
        #pragma unroll
        for(int c=0;c<32;c++){
          u32 pk = *(const u32*)(kcol + c*KSTR);
          a0 = fmaf(qr[c], lo16(pk), a0);
          a1 = fmaf(qr[c], hi16(pk), a1);
        }
        {
          int jz = j0/49; int jr = j0 - jz*49; int jy = jr/7; int jx = jr - jy*7;
          int ridx = (iz-jz+6)*169 + (iy-jy+6)*13 + (ix-jx+6);
          s0 = a0 + rpb[ridx*6+hh] + mask[maskrow + j0];
        }
        if(j0+1 < NWIN){
          int j1 = j0+1;
          int jz = j1/49; int jr = j1 - jz*49; int jy = jr/7; int jx = jr - jy*7;
          int ridx = (iz-jz+6)*169 + (iy-jy+6)*13 + (ix-jx+6);
          s1 = a1 + rpb[ridx*6+hh] + mask[maskrow + j1];
        }
      }
      sc[2*t]=s0; sc[2*t+1]=s1;
      mx = fmaxf(mx, fmaxf(s0, s1));
    }
    #pragma unroll
    for(int m=1;m<32;m<<=1) mx = fmaxf(mx, __shfl_xor(mx, m));

    float sum = 0.f;
    #pragma unroll
    for(int t=0;t<12;t++){ float e = __expf(sc[t]-mx); sc[t]=e; sum += e; }
    #pragma unroll
    for(int m=1;m<32;m<<=1) sum += __shfl_xor(sum, m);
    float rinv = 1.0f / sum;

    #pragma unroll
    for(int t=0;t<6;t++){
      int j0 = 2*l + 64*t;
      if(j0 < NWIN){
        if(j0+1 < NWIN){ float2 w2 = make_float2(sc[2*t], sc[2*t+1]); *(float2*)&ps[g][j0] = w2; }
        else ps[g][j0] = sc[2*t];
      }
    }

    float o = 0.f;
    const float* psr = ps[g];
    const u16* vsr = &Vs[l*VSTR];
    #pragma unroll 4
    for(int j4=0;j4<344;j4+=4){
      float4 p4 = *(const float4*)(psr + j4);
      ushort4 v4 = *(const ushort4*)(vsr + j4);
      o = fmaf(p4.x, bu(v4.x), o);
      o = fmaf(p4.y, bu(v4.y), o);
      o = fmaf(p4.z, bu(v4.z), o);
      o = fmaf(p4.w, bu(v4.w), o);
    }
    if(rowok) out[(rowbase + i0)*DIMC + hh*32 + l] = fb(o * rinv);
  }
}

// ---------------- fused MLP: gelu(xm@W1+b1)@W2+b2, h kept in LDS ----------------
__global__ __launch_bounds__(192) void mlp_fused(const u16* __restrict__ xm, const float* __restrict__ w1,
                                                 const float* __restrict__ b1, const float* __restrict__ w2,
                                                 const float* __restrict__ b2, u16* __restrict__ out){
  __shared__ float a_s[16*192];
  __shared__ float h_s[16*768];
  const int tid = threadIdx.x;
  const long row0 = (long)blockIdx.x*16;
  for(int idx=tid; idx<16*192; idx+=192) a_s[idx] = bu(xm[row0*192 + idx]);
  __syncthreads();

  for(int jj=0;jj<4;jj++){
    const int j = jj*192 + tid;
    float acc[16];
    #pragma unroll
    for(int r=0;r<16;r++) acc[r]=0.f;
    for(int k4=0;k4<192;k4+=4){
      float w0 = w1[(long)(k4+0)*768 + j];
      float wa = w1[(long)(k4+1)*768 + j];
      float wbv= w1[(long)(k4+2)*768 + j];
      float wc = w1[(long)(k4+3)*768 + j];
      #pragma unroll
      for(int r=0;r<16;r++){
        float4 av = *(const float4*)&a_s[r*192+k4];
        float a = acc[r];
        a = fmaf(av.x, w0, a);
        a = fmaf(av.y, wa, a);
        a = fmaf(av.z, wbv, a);
        a = fmaf(av.w, wc, a);
        acc[r] = a;
      }
    }
    float bv = b1[j];
    #pragma unroll
    for(int r=0;r<16;r++) h_s[r*768 + j] = gelu_f(acc[r] + bv);
  }
  __syncthreads();

  float acc2[16];
  #pragma unroll
  for(int r=0;r<16;r++) acc2[r]=0.f;
  for(int k4=0;k4<768;k4+=4){
    float w0 = w2[(long)(k4+0)*192 + tid];
    float wa = w2[(long)(k4+1)*192 + tid];
    float wbv= w2[(long)(k4+2)*192 + tid];
    float wc = w2[(long)(k4+3)*192 + tid];
    #pragma unroll
    for(int r=0;r<16;r++){
      float4 hv = *(const float4*)&h_s[r*768+k4];
      float a = acc2[r];
      a = fmaf(hv.x, w0, a);
      a = fmaf(hv.y, wa, a);
      a = fmaf(hv.z, wbv, a);
      a = fmaf(hv.w, wc, a);
      acc2[r] = a;
    }
  }
  float bv2 = b2[tid];
  #pragma unroll
  for(int r=0;r<16;r++) out[(row0+r)*192 + tid] = fb(acc2[r] + bv2);
}

// ---------------- depthwise 3x3x3 conv, NDHWC, bf16 act / f32 weights ----------------
__global__ __launch_bounds__(256) void dw3(const u16* __restrict__ in, const float* __restrict__ kw,
                                           const float* __restrict__ bias, u16* __restrict__ out){
  int gid = blockIdx.x*256 + threadIdx.x;
  int c = gid % 192;
  int t = gid / 192;
  int b = t / LTOK;
  int s = t - b*LTOK;
  int z = s / 784;
  int r2 = s - z*784;
  int y = r2 / 28;
  int x = r2 - y*28;
  const u16* base = in + ((long)b*LTOK)*192 + c;
  float acc = bias[c];
  #pragma unroll
  for(int dz=-1;dz<=1;dz++){
    int zz=z+dz; if((unsigned)zz>=28u) continue;
    #pragma unroll
    for(int dy=-1;dy<=1;dy++){
      int yy=y+dy; if((unsigned)yy>=28u) continue;
      #pragma unroll
      for(int dx=-1;dx<=1;dx++){
        int xx=x+dx; if((unsigned)xx>=28u) continue;
        acc = fmaf(bu(base[(zz*784+yy*28+xx)*192]), kw[c*27+(dz+1)*9+(dy+1)*3+(dx+1)], acc);
      }
    }
  }
  out[gid] = fb(acc);
}

// ---------------- final: x1 + lin + NCDHW-view gather of t2 -> f32 out ----------------
__global__ __launch_bounds__(256) void final_add(const u16* __restrict__ x1, const u16* __restrict__ lin,
                                                 const u16* __restrict__ t2, float* __restrict__ out){
  int gid = blockIdx.x*256 + threadIdx.x;
  int b  = gid / 4214784;
  int gg = gid - b*4214784;
  int ch = gg / LTOK;
  int sp = gg - ch*LTOK;
  out[gid] = bu(x1[gid]) + bu(lin[gid]) + bu(t2[((long)b*LTOK + sp)*192 + ch]);
}

extern "C" void kernel_launch(void* const* d_in, const int* in_sizes, int n_in,
                              void* d_out, int out_size, void* d_ws, size_t ws_size,
                              hipStream_t stream){
  const float* x      = (const float*)d_in[0];
  const float* mask   = (const float*)d_in[1];
  const float* n1g    = (const float*)d_in[2];
  const float* n1b    = (const float*)d_in[3];
  const float* qkv_w  = (const float*)d_in[4];
  const float* qkv_b  = (const float*)d_in[5];
  const float* rpb    = (const float*)d_in[6];
  const float* proj_w = (const float*)d_in[7];
  const float* proj_b = (const float*)d_in[8];
  const float* n2g    = (const float*)d_in[9];
  const float* n2b    = (const float*)d_in[10];
  const float* l1w    = (const float*)d_in[11];
  const float* l1b    = (const float*)d_in[12];
  const float* l2w    = (const float*)d_in[13];
  const float* l2b    = (const float*)d_in[14];
  const float* dw1k   = (const float*)d_in[15];
  const float* dw1b   = (const float*)d_in[16];
  const float* pw1k   = (const float*)d_in[17];
  const float* pw1b   = (const float*)d_in[18];
  const float* dw2k   = (const float*)d_in[19];
  const float* dw2b   = (const float*)d_in[20];
  const float* pw2k   = (const float*)d_in[21];
  const float* pw2b   = (const float*)d_in[22];

  const size_t FB = (size_t)ROWSZ * DIMC;   // 8,429,568 elems; total ws = 6*FB u16 = 101 MB
  u16* x1b   = (u16*)d_ws;
  u16* winb  = x1b + FB;
  u16* attnb = winb + FB;
  u16* qkvb  = attnb + FB;      // 3*FB
  u16* cb1   = qkvb;
  u16* cb2   = qkvb + FB;
  u16* xmb   = winb;
  u16* linb  = attnb;

  ln_win<<<ROWSZ/4,256,0,stream>>>(x, n1g, n1b, winb);
  gemm16<3,1,0><<<ROWSZ/16,192,0,stream>>>(winb, qkv_w, qkv_b, qkvb, nullptr);
  attn_kernel<<<128*6,256,0,stream>>>(qkvb, rpb, mask, attnb);
  gemm16<1,2,0><<<ROWSZ/16,192,0,stream>>>(attnb, proj_w, proj_b, x1b, x);
  ln_plain<<<ROWSZ/4,256,0,stream>>>(x1b, n2g, n2b, xmb);
  mlp_fused<<<ROWSZ/16,192,0,stream>>>(xmb, l1w, l1b, l2w, l2b, linb);
  dw3<<<TOTE/256,256,0,stream>>>(xmb, dw1k, dw1b, cb1);
  gemm16<1,0,1><<<ROWSZ/16,192,0,stream>>>(cb1, pw1k, pw1b, cb2, nullptr);
  dw3<<<TOTE/256,256,0,stream>>>(cb2, dw2k, dw2b, cb1);
  gemm16<1,0,1><<<ROWSZ/16,192,0,stream>>>(cb1, pw2k, pw2b, cb2, nullptr);
  final_add<<<TOTE/256,256,0,stream>>>(x1b, linb, cb2, (float*)d_out);
}

// Round 6
// 1333.905 us; speedup vs baseline: 1.9036x; 1.9036x over previous
//
#include <hip/hip_runtime.h>

typedef unsigned short u16;
typedef unsigned int   u32;

#define DIMC 192
#define NWIN 343
#define LTOK 21952
#define ROWSZ 43904            // B * L rows
#define TOTE 8429568           // ROWSZ * DIMC
#define QSCALE 0.17677669529663689f
#define EPSF 1e-5f
#define KSTR 352               // Ks transposed stride (bf16 elems)
#define VSTR 356               // Vs transposed stride (bf16 elems)

typedef __attribute__((ext_vector_type(8))) short bf16x8v;
typedef __attribute__((ext_vector_type(4))) float f32x4v;

__device__ __forceinline__ float bu(u16 v){ union{u32 u; float f;} x; x.u = ((u32)v)<<16; return x.f; }
__device__ __forceinline__ float lo16(u32 p){ union{u32 u; float f;} x; x.u = p<<16; return x.f; }
__device__ __forceinline__ float hi16(u32 p){ union{u32 u; float f;} x; x.u = p & 0xffff0000u; return x.f; }
__device__ __forceinline__ u16 fb(float f){
  union{float ff; u32 u;} x; x.ff = f;
  u32 r = (x.u + 0x7fffu + ((x.u>>16)&1u)) >> 16;
  return (u16)r;
}
__device__ __forceinline__ float gelu_f(float x){ return 0.5f*x*(1.0f + erff(x*0.70710678118654752f)); }

__device__ __forceinline__ f32x4v mfma_bf16(bf16x8v a, bf16x8v b, f32x4v c){
  return __builtin_amdgcn_mfma_f32_16x16x32_bf16(a, b, c, 0, 0, 0);
}

// windowed-row -> (batch, token) bijection (shift -3 + partition).
__device__ __forceinline__ void row_to_token(int row, int& b, int& l){
  int bw = row / NWIN, n = row % NWIN;
  b = bw >> 6; int wi = bw & 63;
  int sd = (wi>>4)*7      + n/49;
  int sh = ((wi>>2)&3)*7  + (n/7)%7;
  int sw = (wi&3)*7       + n%7;
  int d = sd+3; if(d>=28) d-=28;
  int h = sh+3; if(h>=28) h-=28;
  int w = sw+3; if(w>=28) w-=28;
  l = d*784 + h*28 + w;
}

// ---------------- weight pre-pack into B-fragment order (bf16) ----------------
// B[k][n]: lane l holds k = ks*32 + (l>>4)*8 + j, n = nt*16 + (l&15); linear
// dst idx = ((nt*KS + ks)*64 + l)*8 + j.  TR=1: source stored (n, k) row-major.
template<int TR>
__global__ __launch_bounds__(256) void pack_w(const float* __restrict__ W, u16* __restrict__ dst,
                                              int K, int N){
  int gid = blockIdx.x*256 + threadIdx.x;
  if(gid >= K*N) return;
  int k = gid / N, n = gid - k*N;
  float v = TR ? W[(long)n*K + k] : W[(long)k*N + n];
  int nt = n >> 4, ks = k >> 5;
  int l  = (((k>>3)&3)<<4) | (n&15);
  int j  = k & 7;
  int KS = K >> 5;
  dst[((((nt*KS + ks)<<6) + l)<<3) + j] = fb(v);
}

// ---------------- LN1: f32 x -> bf16 windowed ----------------
__global__ __launch_bounds__(256) void ln_win(const float* __restrict__ x, const float* __restrict__ g,
                                              const float* __restrict__ bb, u16* __restrict__ out){
  int row  = blockIdx.x*4 + (threadIdx.x>>6);
  int lane = threadIdx.x & 63;
  int b, l; row_to_token(row, b, l);
  const float* p = x + ((long)b*LTOK + l)*DIMC;
  float v0 = p[lane], v1 = p[lane+64], v2 = p[lane+128];
  float s = v0+v1+v2;
  #pragma unroll
  for(int m=1;m<64;m<<=1) s += __shfl_xor(s,m);
  float mean = s*(1.f/192.f);
  float d0=v0-mean, d1=v1-mean, d2=v2-mean;
  float q = d0*d0+d1*d1+d2*d2;
  #pragma unroll
  for(int m=1;m<64;m<<=1) q += __shfl_xor(q,m);
  float rstd = rsqrtf(q*(1.f/192.f)+EPSF);
  u16* o = out + (long)row*DIMC;
  o[lane]     = fb(d0*rstd*g[lane]     + bb[lane]);
  o[lane+64]  = fb(d1*rstd*g[lane+64]  + bb[lane+64]);
  o[lane+128] = fb(d2*rstd*g[lane+128] + bb[lane+128]);
}

// ---------------- LN2: bf16 x1 -> bf16 xm ----------------
__global__ __launch_bounds__(256) void ln_plain(const u16* __restrict__ in, const float* __restrict__ g,
                                                const float* __restrict__ bb, u16* __restrict__ out){
  int row  = blockIdx.x*4 + (threadIdx.x>>6);
  int lane = threadIdx.x & 63;
  const u16* p = in + (long)row*DIMC;
  float v0 = bu(p[lane]), v1 = bu(p[lane+64]), v2 = bu(p[lane+128]);
  float s = v0+v1+v2;
  #pragma unroll
  for(int m=1;m<64;m<<=1) s += __shfl_xor(s,m);
  float mean = s*(1.f/192.f);
  float d0=v0-mean, d1=v1-mean, d2=v2-mean;
  float q = d0*d0+d1*d1+d2*d2;
  #pragma unroll
  for(int m=1;m<64;m<<=1) q += __shfl_xor(q,m);
  float rstd = rsqrtf(q*(1.f/192.f)+EPSF);
  u16* o = out + (long)row*DIMC;
  o[lane]     = fb(d0*rstd*g[lane]     + bb[lane]);
  o[lane+64]  = fb(d1*rstd*g[lane+64]  + bb[lane+64]);
  o[lane+128] = fb(d2*rstd*g[lane+128] + bb[lane+128]);
}

// ---------------- MFMA GEMM: 32 rows/block, K=192, 4 waves ----------------
// EPI 0: out[(row)*NTOT + n] = acc + bias ; EPI 1: proj epilogue (window-reverse
// scatter + f32 residual).
template<int NTOT, int EPI>
__global__ __launch_bounds__(256) void gemm_mfma(const u16* __restrict__ A, const u16* __restrict__ Wp,
                                                 const float* __restrict__ bias, u16* __restrict__ out,
                                                 const float* __restrict__ resid){
  constexpr int KS  = 6;
  constexpr int NPW = NTOT/64;
  __shared__ u16 As[32*192];
  const int tid = threadIdx.x;
  const int w = tid>>6, l = tid&63;
  const int lm = l&15, lh = l>>4;
  const long row0 = (long)blockIdx.x*32;

  {
    const uint4* src = (const uint4*)(A + row0*192);
    #pragma unroll
    for(int c=0;c<3;c++){
      int cz = tid + c*256;               // 768 chunks of 8 u16
      int row = cz/24;
      int byte = (cz*16) ^ ((row&7)<<4);  // XOR swizzle vs 384B row stride
      *(uint4*)((char*)As + byte) = src[cz];
    }
  }
  __syncthreads();

  f32x4v acc[NPW][2];
  const f32x4v z4 = {0.f,0.f,0.f,0.f};
  #pragma unroll
  for(int i=0;i<NPW;i++){ acc[i][0]=z4; acc[i][1]=z4; }

  #pragma unroll
  for(int ks=0;ks<KS;ks++){
    bf16x8v a[2];
    #pragma unroll
    for(int mt=0;mt<2;mt++){
      int row = mt*16 + lm;
      int byte = (row*384 + ks*64 + lh*16) ^ ((row&7)<<4);
      a[mt] = *(const bf16x8v*)((const char*)As + byte);
    }
    #pragma unroll
    for(int i=0;i<NPW;i++){
      int nt = w*NPW + i;
      bf16x8v b = *(const bf16x8v*)(Wp + ((((nt*KS + ks)<<6) + l)<<3));
      acc[i][0] = mfma_bf16(a[0], b, acc[i][0]);
      acc[i][1] = mfma_bf16(a[1], b, acc[i][1]);
    }
  }

  #pragma unroll
  for(int i=0;i<NPW;i++){
    int n = (w*NPW + i)*16 + lm;
    float bv = bias[n];
    #pragma unroll
    for(int mt=0;mt<2;mt++){
      #pragma unroll
      for(int r=0;r<4;r++){
        long mrow = row0 + mt*16 + lh*4 + r;
        float v = acc[i][mt][r] + bv;
        if constexpr(EPI==0){
          out[mrow*NTOT + n] = fb(v);
        } else {
          int b_, lt; row_to_token((int)mrow, b_, lt);
          long li = ((long)b_*LTOK + lt)*DIMC + n;
          out[li] = fb(v + resid[li]);
        }
      }
    }
  }
}

// ---------------- fused MLP via MFMA: h (32x768 bf16) kept in LDS ----------------
__global__ __launch_bounds__(256) void mlp_mfma(const u16* __restrict__ xm, const u16* __restrict__ Wp1,
                                                const float* __restrict__ b1, const u16* __restrict__ Wp2,
                                                const float* __restrict__ b2, u16* __restrict__ out){
  __shared__ u16 As[32*192];    // 12 KB
  __shared__ u16 Hs[32*768];    // 48 KB
  const int tid = threadIdx.x;
  const int w = tid>>6, l = tid&63;
  const int lm = l&15, lh = l>>4;
  const long row0 = (long)blockIdx.x*32;

  {
    const uint4* src = (const uint4*)(xm + row0*192);
    #pragma unroll
    for(int c=0;c<3;c++){
      int cz = tid + c*256;
      int row = cz/24;
      int byte = (cz*16) ^ ((row&7)<<4);
      *(uint4*)((char*)As + byte) = src[cz];
    }
  }
  __syncthreads();

  const f32x4v z4 = {0.f,0.f,0.f,0.f};
  f32x4v acc1[12][2];
  #pragma unroll
  for(int i=0;i<12;i++){ acc1[i][0]=z4; acc1[i][1]=z4; }

  #pragma unroll
  for(int ks=0;ks<6;ks++){
    bf16x8v a[2];
    #pragma unroll
    for(int mt=0;mt<2;mt++){
      int row = mt*16 + lm;
      int byte = (row*384 + ks*64 + lh*16) ^ ((row&7)<<4);
      a[mt] = *(const bf16x8v*)((const char*)As + byte);
    }
    #pragma unroll
    for(int i=0;i<12;i++){
      int nt = w*12 + i;
      bf16x8v b = *(const bf16x8v*)(Wp1 + ((((nt*6 + ks)<<6) + l)<<3));
      acc1[i][0] = mfma_bf16(a[0], b, acc1[i][0]);
      acc1[i][1] = mfma_bf16(a[1], b, acc1[i][1]);
    }
  }

  // gelu(acc1 + b1) -> Hs (row stride 1536 B, XOR swizzled)
  #pragma unroll
  for(int i=0;i<12;i++){
    int n = (w*12 + i)*16 + lm;
    float bv = b1[n];
    #pragma unroll
    for(int mt=0;mt<2;mt++){
      #pragma unroll
      for(int r=0;r<4;r++){
        int mrow = mt*16 + lh*4 + r;
        float h = gelu_f(acc1[i][mt][r] + bv);
        int byte = (mrow*1536 + n*2) ^ ((mrow&7)<<4);
        *(u16*)((char*)Hs + byte) = fb(h);
      }
    }
  }
  __syncthreads();

  f32x4v acc2[3][2];
  #pragma unroll
  for(int i=0;i<3;i++){ acc2[i][0]=z4; acc2[i][1]=z4; }

  #pragma unroll 4
  for(int ks=0;ks<24;ks++){
    bf16x8v a[2];
    #pragma unroll
    for(int mt=0;mt<2;mt++){
      int row = mt*16 + lm;
      int byte = (row*1536 + ks*64 + lh*16) ^ ((row&7)<<4);
      a[mt] = *(const bf16x8v*)((const char*)Hs + byte);
    }
    #pragma unroll
    for(int i=0;i<3;i++){
      int nt = w*3 + i;
      bf16x8v b = *(const bf16x8v*)(Wp2 + ((((nt*24 + ks)<<6) + l)<<3));
      acc2[i][0] = mfma_bf16(a[0], b, acc2[i][0]);
      acc2[i][1] = mfma_bf16(a[1], b, acc2[i][1]);
    }
  }

  #pragma unroll
  for(int i=0;i<3;i++){
    int n = (w*3 + i)*16 + lm;
    float bv = b2[n];
    #pragma unroll
    for(int mt=0;mt<2;mt++){
      #pragma unroll
      for(int r=0;r<4;r++){
        long mrow = row0 + mt*16 + lh*4 + r;
        out[mrow*192 + n] = fb(acc2[i][mt][r] + bv);
      }
    }
  }
}

// ---------------- attention: one block per (window-batch, head) ----------------
__global__ __launch_bounds__(256) void attn_kernel(const u16* __restrict__ qkv, const float* __restrict__ rpb,
                                                   const float* __restrict__ mask, u16* __restrict__ out){
  __shared__ u16 Ks[32*KSTR];
  __shared__ u16 Vs[32*VSTR];
  __shared__ float ps[8][344];
  __shared__ float qs[8][32];

  const int tid = threadIdx.x;
  const int bw = blockIdx.x / 6, hh = blockIdx.x % 6;
  const int wi = bw & 63;
  const long rowbase = (long)bw*NWIN;

  for(int idx=tid; idx<NWIN*32; idx+=256){
    int j = idx >> 5, d = idx & 31;
    long p = (rowbase + j)*576 + hh*32 + d;
    Ks[d*KSTR + j] = qkv[p + 192];
    Vs[d*VSTR + j] = qkv[p + 384];
  }
  if(tid < 32){ Ks[tid*KSTR + 343] = 0; Vs[tid*VSTR + 343] = 0; }
  if(tid < 8) ps[tid][343] = 0.f;
  __syncthreads();

  const int wv   = tid >> 6;
  const int lane = tid & 63;
  const int half = lane >> 5;
  const int l    = lane & 31;
  const int g    = wv*2 + half;

  for(int it=0; it<43; ++it){
    int i0 = it*8 + g;
    bool rowok = i0 < NWIN;
    int i = rowok ? i0 : (NWIN-1);

    qs[g][l] = bu(qkv[(rowbase + i)*576 + hh*32 + l]) * QSCALE;
    float qr[32];
    {
      const float4* qp = (const float4*)qs[g];
      #pragma unroll
      for(int c4=0;c4<8;c4++){
        float4 t4 = qp[c4];
        qr[c4*4+0]=t4.x; qr[c4*4+1]=t4.y; qr[c4*4+2]=t4.z; qr[c4*4+3]=t4.w;
      }
    }

    const int iz = i/49, iy = (i/7)%7, ix = i%7;
    const long maskrow = ((long)wi*NWIN + i)*NWIN;

    // QK^T: c-outer, 12 independent accumulation chains (invalid j read
    // in-LDS garbage; masked below before use).
    float sc[12];
    #pragma unroll
    for(int t=0;t<12;t++) sc[t]=0.f;
    #pragma unroll 4
    for(int c=0;c<32;c++){
      float qc = qr[c];
      const u16* kr = Ks + c*KSTR + 2*l;
      #pragma unroll
      for(int t=0;t<6;t++){
        u32 pk = *(const u32*)(kr + 64*t);
        sc[2*t]   = fmaf(qc, lo16(pk), sc[2*t]);
        sc[2*t+1] = fmaf(qc, hi16(pk), sc[2*t+1]);
      }
    }

    float mx = -1e30f;
    #pragma unroll
    for(int t=0;t<6;t++){
      int j0 = 2*l + 64*t;
      float s0 = -1e30f, s1 = -1e30f;
      if(j0 < NWIN){
        int jz = j0/49, jr = j0 - jz*49, jy = jr/7, jx = jr - jy*7;
        s0 = sc[2*t] + rpb[((iz-jz+6)*169 + (iy-jy+6)*13 + (ix-jx+6))*6+hh] + mask[maskrow + j0];
        if(j0+1 < NWIN){
          int j1 = j0+1;
          jz = j1/49; jr = j1 - jz*49; jy = jr/7; jx = jr - jy*7;
          s1 = sc[2*t+1] + rpb[((iz-jz+6)*169 + (iy-jy+6)*13 + (ix-jx+6))*6+hh] + mask[maskrow + j1];
        }
      }
      sc[2*t]=s0; sc[2*t+1]=s1;
      mx = fmaxf(mx, fmaxf(s0, s1));
    }
    #pragma unroll
    for(int m=1;m<32;m<<=1) mx = fmaxf(mx, __shfl_xor(mx, m));

    float sum = 0.f;
    #pragma unroll
    for(int t=0;t<12;t++){ float e = __expf(sc[t]-mx); sc[t]=e; sum += e; }
    #pragma unroll
    for(int m=1;m<32;m<<=1) sum += __shfl_xor(sum, m);
    float rinv = 1.0f / sum;

    #pragma unroll
    for(int t=0;t<6;t++){
      int j0 = 2*l + 64*t;
      if(j0 < NWIN){
        if(j0+1 < NWIN){ float2 w2 = make_float2(sc[2*t], sc[2*t+1]); *(float2*)&ps[g][j0] = w2; }
        else ps[g][j0] = sc[2*t];
      }
    }

    // PV: 8 independent accumulators
    float o[8];
    #pragma unroll
    for(int u=0;u<8;u++) o[u]=0.f;
    const float* psr = ps[g];
    const u16* vsr = &Vs[l*VSTR];
    #pragma unroll 2
    for(int j8=0;j8<344;j8+=8){
      float4 pa = *(const float4*)(psr + j8);
      float4 pb = *(const float4*)(psr + j8 + 4);
      ushort4 va = *(const ushort4*)(vsr + j8);
      ushort4 vb = *(const ushort4*)(vsr + j8 + 4);
      o[0] = fmaf(pa.x, bu(va.x), o[0]);
      o[1] = fmaf(pa.y, bu(va.y), o[1]);
      o[2] = fmaf(pa.z, bu(va.z), o[2]);
      o[3] = fmaf(pa.w, bu(va.w), o[3]);
      o[4] = fmaf(pb.x, bu(vb.x), o[4]);
      o[5] = fmaf(pb.y, bu(vb.y), o[5]);
      o[6] = fmaf(pb.z, bu(vb.z), o[6]);
      o[7] = fmaf(pb.w, bu(vb.w), o[7]);
    }
    float ot = ((o[0]+o[1])+(o[2]+o[3])) + ((o[4]+o[5])+(o[6]+o[7]));
    if(rowok) out[(rowbase + i0)*DIMC + hh*32 + l] = fb(ot * rinv);
  }
}

// ---------------- depthwise 3x3x3 conv, NDHWC, bf16 act / f32 weights ----------------
__global__ __launch_bounds__(256) void dw3(const u16* __restrict__ in, const float* __restrict__ kw,
                                           const float* __restrict__ bias, u16* __restrict__ out){
  int gid = blockIdx.x*256 + threadIdx.x;
  int c = gid % 192;
  int t = gid / 192;
  int b = t / LTOK;
  int s = t - b*LTOK;
  int z = s / 784;
  int r2 = s - z*784;
  int y = r2 / 28;
  int x = r2 - y*28;
  const u16* base = in + ((long)b*LTOK)*192 + c;
  float acc = bias[c];
  #pragma unroll
  for(int dz=-1;dz<=1;dz++){
    int zz=z+dz; if((unsigned)zz>=28u) continue;
    #pragma unroll
    for(int dy=-1;dy<=1;dy++){
      int yy=y+dy; if((unsigned)yy>=28u) continue;
      #pragma unroll
      for(int dx=-1;dx<=1;dx++){
        int xx=x+dx; if((unsigned)xx>=28u) continue;
        acc = fmaf(bu(base[(zz*784+yy*28+xx)*192]), kw[c*27+(dz+1)*9+(dy+1)*3+(dx+1)], acc);
      }
    }
  }
  out[gid] = fb(acc);
}

// ---------------- final: x1 + lin + NCDHW-view gather of t2 -> f32 out ----------------
__global__ __launch_bounds__(256) void final_add(const u16* __restrict__ x1, const u16* __restrict__ lin,
                                                 const u16* __restrict__ t2, float* __restrict__ out){
  int gid = blockIdx.x*256 + threadIdx.x;
  int b  = gid / 4214784;
  int gg = gid - b*4214784;
  int ch = gg / LTOK;
  int sp = gg - ch*LTOK;
  out[gid] = bu(x1[gid]) + bu(lin[gid]) + bu(t2[((long)b*LTOK + sp)*192 + ch]);
}

extern "C" void kernel_launch(void* const* d_in, const int* in_sizes, int n_in,
                              void* d_out, int out_size, void* d_ws, size_t ws_size,
                              hipStream_t stream){
  const float* x      = (const float*)d_in[0];
  const float* mask   = (const float*)d_in[1];
  const float* n1g    = (const float*)d_in[2];
  const float* n1b    = (const float*)d_in[3];
  const float* qkv_w  = (const float*)d_in[4];
  const float* qkv_b  = (const float*)d_in[5];
  const float* rpb    = (const float*)d_in[6];
  const float* proj_w = (const float*)d_in[7];
  const float* proj_b = (const float*)d_in[8];
  const float* n2g    = (const float*)d_in[9];
  const float* n2b    = (const float*)d_in[10];
  const float* l1w    = (const float*)d_in[11];
  const float* l1b    = (const float*)d_in[12];
  const float* l2w    = (const float*)d_in[13];
  const float* l2b    = (const float*)d_in[14];
  const float* dw1k   = (const float*)d_in[15];
  const float* dw1b   = (const float*)d_in[16];
  const float* pw1k   = (const float*)d_in[17];
  const float* pw1b   = (const float*)d_in[18];
  const float* dw2k   = (const float*)d_in[19];
  const float* dw2b   = (const float*)d_in[20];
  const float* pw2k   = (const float*)d_in[21];
  const float* pw2b   = (const float*)d_in[22];

  const size_t FB = (size_t)ROWSZ * DIMC;   // 8,429,568 elems
  u16* x1b   = (u16*)d_ws;
  u16* winb  = x1b + FB;
  u16* attnb = winb + FB;
  u16* qkvb  = attnb + FB;      // 3*FB
  u16* cb1   = qkvb;
  u16* cb2   = qkvb + FB;
  u16* xmb   = winb;
  u16* linb  = attnb;
  // packed weights after 6*FB (516096 u16 ~ 1 MB)
  u16* pk_qkv  = x1b + 6*FB;
  u16* pk_proj = pk_qkv  + 110592;
  u16* pk_l1   = pk_proj + 36864;
  u16* pk_l2   = pk_l1   + 147456;
  u16* pk_pw1  = pk_l2   + 147456;
  u16* pk_pw2  = pk_pw1  + 36864;

  pack_w<0><<<432,256,0,stream>>>(qkv_w,  pk_qkv,  192, 576);
  pack_w<0><<<144,256,0,stream>>>(proj_w, pk_proj, 192, 192);
  pack_w<0><<<576,256,0,stream>>>(l1w,    pk_l1,   192, 768);
  pack_w<0><<<576,256,0,stream>>>(l2w,    pk_l2,   768, 192);
  pack_w<1><<<144,256,0,stream>>>(pw1k,   pk_pw1,  192, 192);
  pack_w<1><<<144,256,0,stream>>>(pw2k,   pk_pw2,  192, 192);

  ln_win<<<ROWSZ/4,256,0,stream>>>(x, n1g, n1b, winb);
  gemm_mfma<576,0><<<ROWSZ/32,256,0,stream>>>(winb, pk_qkv, qkv_b, qkvb, nullptr);
  attn_kernel<<<128*6,256,0,stream>>>(qkvb, rpb, mask, attnb);
  gemm_mfma<192,1><<<ROWSZ/32,256,0,stream>>>(attnb, pk_proj, proj_b, x1b, x);
  ln_plain<<<ROWSZ/4,256,0,stream>>>(x1b, n2g, n2b, xmb);
  mlp_mfma<<<ROWSZ/32,256,0,stream>>>(xmb, pk_l1, l1b, pk_l2, l2b, linb);
  dw3<<<TOTE/256,256,0,stream>>>(xmb, dw1k, dw1b, cb1);
  gemm_mfma<192,0><<<ROWSZ/32,256,0,stream>>>(cb1, pk_pw1, pw1b, cb2, nullptr);
  dw3<<<TOTE/256,256,0,stream>>>(cb2, dw2k, dw2b, cb1);
  gemm_mfma<192,0><<<ROWSZ/32,256,0,stream>>>(cb1, pk_pw2, pw2b, cb2, nullptr);
  final_add<<<TOTE/256,256,0,stream>>>(x1b, linb, cb2, (float*)d_out);
}

// Round 8
// 817.290 us; speedup vs baseline: 3.1069x; 1.6321x over previous
//
#include <hip/hip_runtime.h>

typedef unsigned short u16;
typedef unsigned int   u32;

#define DIMC 192
#define NWIN 343
#define LTOK 21952
#define ROWSZ 43904            // B * L rows
#define TOTE 8429568           // ROWSZ * DIMC
#define QSCALE 0.17677669529663689f
#define EPSF 1e-5f

typedef __attribute__((ext_vector_type(8))) short bf16x8v;
typedef __attribute__((ext_vector_type(4))) float f32x4v;

__device__ __forceinline__ float bu(u16 v){ union{u32 u; float f;} x; x.u = ((u32)v)<<16; return x.f; }
__device__ __forceinline__ u16 fb(float f){
  union{float ff; u32 u;} x; x.ff = f;
  u32 r = (x.u + 0x7fffu + ((x.u>>16)&1u)) >> 16;
  return (u16)r;
}
__device__ __forceinline__ float gelu_f(float x){ return 0.5f*x*(1.0f + erff(x*0.70710678118654752f)); }

__device__ __forceinline__ f32x4v mfma_bf16(bf16x8v a, bf16x8v b, f32x4v c){
  return __builtin_amdgcn_mfma_f32_16x16x32_bf16(a, b, c, 0, 0, 0);
}

// windowed-row -> (batch, token) bijection (shift -3 + partition).
__device__ __forceinline__ void row_to_token(int row, int& b, int& l){
  int bw = row / NWIN, n = row % NWIN;
  b = bw >> 6; int wi = bw & 63;
  int sd = (wi>>4)*7      + n/49;
  int sh = ((wi>>2)&3)*7  + (n/7)%7;
  int sw = (wi&3)*7       + n%7;
  int d = sd+3; if(d>=28) d-=28;
  int h = sh+3; if(h>=28) h-=28;
  int w = sw+3; if(w>=28) w-=28;
  l = d*784 + h*28 + w;
}

// ---------------- weight pre-pack into B-fragment order (bf16) ----------------
template<int TR>
__global__ __launch_bounds__(256) void pack_w(const float* __restrict__ W, u16* __restrict__ dst,
                                              int K, int N){
  int gid = blockIdx.x*256 + threadIdx.x;
  if(gid >= K*N) return;
  int k = gid / N, n = gid - k*N;
  float v = TR ? W[(long)n*K + k] : W[(long)k*N + n];
  int nt = n >> 4, ks = k >> 5;
  int l  = (((k>>3)&3)<<4) | (n&15);
  int j  = k & 7;
  int KS = K >> 5;
  dst[((((nt*KS + ks)<<6) + l)<<3) + j] = fb(v);
}

// ---------------- LN1: f32 x -> bf16 windowed ----------------
__global__ __launch_bounds__(256) void ln_win(const float* __restrict__ x, const float* __restrict__ g,
                                              const float* __restrict__ bb, u16* __restrict__ out){
  int row  = blockIdx.x*4 + (threadIdx.x>>6);
  int lane = threadIdx.x & 63;
  int b, l; row_to_token(row, b, l);
  const float* p = x + ((long)b*LTOK + l)*DIMC;
  float v0 = p[lane], v1 = p[lane+64], v2 = p[lane+128];
  float s = v0+v1+v2;
  #pragma unroll
  for(int m=1;m<64;m<<=1) s += __shfl_xor(s,m);
  float mean = s*(1.f/192.f);
  float d0=v0-mean, d1=v1-mean, d2=v2-mean;
  float q = d0*d0+d1*d1+d2*d2;
  #pragma unroll
  for(int m=1;m<64;m<<=1) q += __shfl_xor(q,m);
  float rstd = rsqrtf(q*(1.f/192.f)+EPSF);
  u16* o = out + (long)row*DIMC;
  o[lane]     = fb(d0*rstd*g[lane]     + bb[lane]);
  o[lane+64]  = fb(d1*rstd*g[lane+64]  + bb[lane+64]);
  o[lane+128] = fb(d2*rstd*g[lane+128] + bb[lane+128]);
}

// ---------------- LN2: bf16 x1 -> bf16 xm ----------------
__global__ __launch_bounds__(256) void ln_plain(const u16* __restrict__ in, const float* __restrict__ g,
                                                const float* __restrict__ bb, u16* __restrict__ out){
  int row  = blockIdx.x*4 + (threadIdx.x>>6);
  int lane = threadIdx.x & 63;
  const u16* p = in + (long)row*DIMC;
  float v0 = bu(p[lane]), v1 = bu(p[lane+64]), v2 = bu(p[lane+128]);
  float s = v0+v1+v2;
  #pragma unroll
  for(int m=1;m<64;m<<=1) s += __shfl_xor(s,m);
  float mean = s*(1.f/192.f);
  float d0=v0-mean, d1=v1-mean, d2=v2-mean;
  float q = d0*d0+d1*d1+d2*d2;
  #pragma unroll
  for(int m=1;m<64;m<<=1) q += __shfl_xor(q,m);
  float rstd = rsqrtf(q*(1.f/192.f)+EPSF);
  u16* o = out + (long)row*DIMC;
  o[lane]     = fb(d0*rstd*g[lane]     + bb[lane]);
  o[lane+64]  = fb(d1*rstd*g[lane+64]  + bb[lane+64]);
  o[lane+128] = fb(d2*rstd*g[lane+128] + bb[lane+128]);
}

// ---------------- MFMA GEMM: 32 rows/block, K=192, 4 waves ----------------
template<int NTOT, int EPI>
__global__ __launch_bounds__(256) void gemm_mfma(const u16* __restrict__ A, const u16* __restrict__ Wp,
                                                 const float* __restrict__ bias, u16* __restrict__ out,
                                                 const float* __restrict__ resid){
  constexpr int KS  = 6;
  constexpr int NPW = NTOT/64;
  __shared__ u16 As[32*192];
  const int tid = threadIdx.x;
  const int w = tid>>6, l = tid&63;
  const int lm = l&15, lh = l>>4;
  const long row0 = (long)blockIdx.x*32;

  {
    const uint4* src = (const uint4*)(A + row0*192);
    #pragma unroll
    for(int c=0;c<3;c++){
      int cz = tid + c*256;
      int row = cz/24;
      int byte = (cz*16) ^ ((row&7)<<4);
      *(uint4*)((char*)As + byte) = src[cz];
    }
  }
  __syncthreads();

  f32x4v acc[NPW][2];
  const f32x4v z4 = {0.f,0.f,0.f,0.f};
  #pragma unroll
  for(int i=0;i<NPW;i++){ acc[i][0]=z4; acc[i][1]=z4; }

  #pragma unroll
  for(int ks=0;ks<KS;ks++){
    bf16x8v a[2];
    #pragma unroll
    for(int mt=0;mt<2;mt++){
      int row = mt*16 + lm;
      int byte = (row*384 + ks*64 + lh*16) ^ ((row&7)<<4);
      a[mt] = *(const bf16x8v*)((const char*)As + byte);
    }
    #pragma unroll
    for(int i=0;i<NPW;i++){
      int nt = w*NPW + i;
      bf16x8v b = *(const bf16x8v*)(Wp + ((((nt*KS + ks)<<6) + l)<<3));
      acc[i][0] = mfma_bf16(a[0], b, acc[i][0]);
      acc[i][1] = mfma_bf16(a[1], b, acc[i][1]);
    }
  }

  #pragma unroll
  for(int i=0;i<NPW;i++){
    int n = (w*NPW + i)*16 + lm;
    float bv = bias[n];
    #pragma unroll
    for(int mt=0;mt<2;mt++){
      #pragma unroll
      for(int r=0;r<4;r++){
        long mrow = row0 + mt*16 + lh*4 + r;
        float v = acc[i][mt][r] + bv;
        if constexpr(EPI==0){
          out[mrow*NTOT + n] = fb(v);
        } else {
          int b_, lt; row_to_token((int)mrow, b_, lt);
          long li = ((long)b_*LTOK + lt)*DIMC + n;
          out[li] = fb(v + resid[li]);
        }
      }
    }
  }
}

// ---------------- fused MLP via MFMA: h (32x768 bf16) kept in LDS ----------------
__global__ __launch_bounds__(256) void mlp_mfma(const u16* __restrict__ xm, const u16* __restrict__ Wp1,
                                                const float* __restrict__ b1, const u16* __restrict__ Wp2,
                                                const float* __restrict__ b2, u16* __restrict__ out){
  __shared__ u16 As[32*192];
  __shared__ u16 Hs[32*768];
  const int tid = threadIdx.x;
  const int w = tid>>6, l = tid&63;
  const int lm = l&15, lh = l>>4;
  const long row0 = (long)blockIdx.x*32;

  {
    const uint4* src = (const uint4*)(xm + row0*192);
    #pragma unroll
    for(int c=0;c<3;c++){
      int cz = tid + c*256;
      int row = cz/24;
      int byte = (cz*16) ^ ((row&7)<<4);
      *(uint4*)((char*)As + byte) = src[cz];
    }
  }
  __syncthreads();

  const f32x4v z4 = {0.f,0.f,0.f,0.f};
  f32x4v acc1[12][2];
  #pragma unroll
  for(int i=0;i<12;i++){ acc1[i][0]=z4; acc1[i][1]=z4; }

  #pragma unroll
  for(int ks=0;ks<6;ks++){
    bf16x8v a[2];
    #pragma unroll
    for(int mt=0;mt<2;mt++){
      int row = mt*16 + lm;
      int byte = (row*384 + ks*64 + lh*16) ^ ((row&7)<<4);
      a[mt] = *(const bf16x8v*)((const char*)As + byte);
    }
    #pragma unroll
    for(int i=0;i<12;i++){
      int nt = w*12 + i;
      bf16x8v b = *(const bf16x8v*)(Wp1 + ((((nt*6 + ks)<<6) + l)<<3));
      acc1[i][0] = mfma_bf16(a[0], b, acc1[i][0]);
      acc1[i][1] = mfma_bf16(a[1], b, acc1[i][1]);
    }
  }

  #pragma unroll
  for(int i=0;i<12;i++){
    int n = (w*12 + i)*16 + lm;
    float bv = b1[n];
    #pragma unroll
    for(int mt=0;mt<2;mt++){
      #pragma unroll
      for(int r=0;r<4;r++){
        int mrow = mt*16 + lh*4 + r;
        float h = gelu_f(acc1[i][mt][r] + bv);
        int byte = (mrow*1536 + n*2) ^ ((mrow&7)<<4);
        *(u16*)((char*)Hs + byte) = fb(h);
      }
    }
  }
  __syncthreads();

  f32x4v acc2[3][2];
  #pragma unroll
  for(int i=0;i<3;i++){ acc2[i][0]=z4; acc2[i][1]=z4; }

  #pragma unroll 4
  for(int ks=0;ks<24;ks++){
    bf16x8v a[2];
    #pragma unroll
    for(int mt=0;mt<2;mt++){
      int row = mt*16 + lm;
      int byte = (row*1536 + ks*64 + lh*16) ^ ((row&7)<<4);
      a[mt] = *(const bf16x8v*)((const char*)Hs + byte);
    }
    #pragma unroll
    for(int i=0;i<3;i++){
      int nt = w*3 + i;
      bf16x8v b = *(const bf16x8v*)(Wp2 + ((((nt*24 + ks)<<6) + l)<<3));
      acc2[i][0] = mfma_bf16(a[0], b, acc2[i][0]);
      acc2[i][1] = mfma_bf16(a[1], b, acc2[i][1]);
    }
  }

  #pragma unroll
  for(int i=0;i<3;i++){
    int n = (w*3 + i)*16 + lm;
    float bv = b2[n];
    #pragma unroll
    for(int mt=0;mt<2;mt++){
      #pragma unroll
      for(int r=0;r<4;r++){
        long mrow = row0 + mt*16 + lh*4 + r;
        out[mrow*192 + n] = fb(acc2[i][mt][r] + bv);
      }
    }
  }
}

// ---------------- MFMA attention: one block per (window, head), 4 waves ----------------
__global__ __launch_bounds__(256) void attn_mfma(const u16* __restrict__ qkv, const float* __restrict__ rpb,
                                                 u16* __restrict__ out){
  __shared__ u16 Qs[352*32];        // Q rows (pad rows zero)
  __shared__ u16 Ks2[352*32];       // K rows (pad rows zero)
  __shared__ u16 Vt[32*360];        // V transposed [d][j], stride 360
  __shared__ u16 Ps[4][16*360];     // per-wave P tile
  __shared__ float rpb_l[2197];     // rpb[:, hh]
  __shared__ u16 reg_l[352];        // region id per token in this window

  const int tid = threadIdx.x;
  const int bw = blockIdx.x / 6, hh = blockIdx.x % 6;
  const int wi = bw & 63;
  const long rowbase = (long)bw*NWIN;

  for(int i=tid;i<2197;i+=256) rpb_l[i] = rpb[i*6+hh];
  for(int i2=tid;i2<352;i2+=256){          // FIX: grid-stride (blockDim=256 < 352)
    int rg = 0;
    if(i2 < 343){
      int sd = (wi>>4)*7      + i2/49;
      int sh = ((wi>>2)&3)*7  + (i2/7)%7;
      int sw = (wi&3)*7       + i2%7;
      int rd = sd<21?0:(sd<25?1:2);
      int rh = sh<21?0:(sh<25?1:2);
      int rw = sw<21?0:(sw<25?1:2);
      rg = rd*9+rh*3+rw;
    }
    reg_l[i2] = (u16)rg;
  }
  if(tid < 144){ ((u32*)Qs)[343*16 + tid] = 0; ((u32*)Ks2)[343*16 + tid] = 0; }
  for(int p2=tid;p2<288;p2+=256){          // FIX: grid-stride (was if(tid<288))
    int d = p2/9, j = 343 + p2%9; Vt[d*360 + j] = 0;
  }

  for(int p = tid; p < 343*16; p += 256){
    int j = p >> 4, dp = p & 15;
    const u32* src = (const u32*)(qkv + (rowbase + j)*576 + hh*32) + dp;
    ((u32*)Qs)[j*16 + dp]  = src[0];
    ((u32*)Ks2)[j*16 + dp] = src[96];     // +192 u16
    u32 vv = src[192];                     // +384 u16
    Vt[(dp*2)*360 + j]   = (u16)(vv & 0xffffu);
    Vt[(dp*2+1)*360 + j] = (u16)(vv >> 16);
  }
  __syncthreads();

  const int w = tid>>6, l = tid&63;
  const int lm = l&15, lh = l>>4;
  u16* Pw = Ps[w];
  const f32x4v z4 = {0.f,0.f,0.f,0.f};

  for(int it = w; it < 22; it += 4){
    const int i0 = it*16;
    bf16x8v aq = *(const bf16x8v*)(Qs + (i0+lm)*32 + lh*8);
    f32x4v acc[22];
    #pragma unroll
    for(int jt=0;jt<22;jt++){
      bf16x8v bk = *(const bf16x8v*)(Ks2 + (jt*16+lm)*32 + lh*8);
      acc[jt] = mfma_bf16(aq, bk, z4);
    }

    int izr[4], iyr[4], ixr[4], irr[4];
    #pragma unroll
    for(int r=0;r<4;r++){
      int i = i0 + lh*4 + r; if(i>342) i=342;
      izr[r]=i/49; int rem=i-izr[r]*49; iyr[r]=rem/7; ixr[r]=rem-iyr[r]*7;
      irr[r]=reg_l[i];
    }
    #pragma unroll
    for(int jt=0;jt<22;jt++){
      int j = jt*16 + lm;
      int jc = j>342?342:j;
      int jz=jc/49; int rem=jc-jz*49; int jy=rem/7; int jx=rem-jy*7;
      int rj = reg_l[jc];
      bool jok = j<343;
      #pragma unroll
      for(int r=0;r<4;r++){
        float bias = rpb_l[(izr[r]-jz+6)*169 + (iyr[r]-jy+6)*13 + (ixr[r]-jx+6)];
        float v = acc[jt][r]*QSCALE + bias + ((irr[r]==rj)?0.f:-100.f);
        acc[jt][r] = jok ? v : -1e30f;
      }
    }

    float rinv[4];
    #pragma unroll
    for(int r=0;r<4;r++){
      float mx = acc[0][r];
      #pragma unroll
      for(int jt=1;jt<22;jt++) mx = fmaxf(mx, acc[jt][r]);
      #pragma unroll
      for(int m=1;m<16;m<<=1) mx = fmaxf(mx, __shfl_xor(mx, m));
      float sm = 0.f;
      #pragma unroll
      for(int jt=0;jt<22;jt++){ float e = __expf(acc[jt][r]-mx); acc[jt][r]=e; sm += e; }
      #pragma unroll
      for(int m=1;m<16;m<<=1) sm += __shfl_xor(sm, m);
      rinv[r] = 1.0f/sm;
    }

    #pragma unroll
    for(int jt=0;jt<22;jt++){
      int j = jt*16+lm;
      #pragma unroll
      for(int r=0;r<4;r++) Pw[(lh*4+r)*360 + j] = fb(acc[jt][r]);
    }

    f32x4v o0=z4, o1=z4;
    #pragma unroll
    for(int ks=0;ks<11;ks++){
      bf16x8v ap = *(const bf16x8v*)(Pw + lm*360 + ks*32 + lh*8);
      bf16x8v b0 = *(const bf16x8v*)(Vt + lm*360 + ks*32 + lh*8);
      bf16x8v b1 = *(const bf16x8v*)(Vt + (16+lm)*360 + ks*32 + lh*8);
      o0 = mfma_bf16(ap, b0, o0);
      o1 = mfma_bf16(ap, b1, o1);
    }

    #pragma unroll
    for(int r=0;r<4;r++){
      int i = i0 + lh*4 + r;
      if(i < 343){
        u16* po = out + (rowbase + i)*192 + hh*32;
        po[lm]    = fb(o0[r]*rinv[r]);
        po[16+lm] = fb(o1[r]*rinv[r]);
      }
    }
  }
}

// ---------------- depthwise 3x3x3 conv, NDHWC, bf16 act / f32 weights ----------------
__global__ __launch_bounds__(256) void dw3(const u16* __restrict__ in, const float* __restrict__ kw,
                                           const float* __restrict__ bias, u16* __restrict__ out){
  int gid = blockIdx.x*256 + threadIdx.x;
  int c = gid % 192;
  int t = gid / 192;
  int b = t / LTOK;
  int s = t - b*LTOK;
  int z = s / 784;
  int r2 = s - z*784;
  int y = r2 / 28;
  int x = r2 - y*28;
  const u16* base = in + ((long)b*LTOK)*192 + c;
  float acc = bias[c];
  #pragma unroll
  for(int dz=-1;dz<=1;dz++){
    int zz=z+dz; if((unsigned)zz>=28u) continue;
    #pragma unroll
    for(int dy=-1;dy<=1;dy++){
      int yy=y+dy; if((unsigned)yy>=28u) continue;
      #pragma unroll
      for(int dx=-1;dx<=1;dx++){
        int xx=x+dx; if((unsigned)xx>=28u) continue;
        acc = fmaf(bu(base[(zz*784+yy*28+xx)*192]), kw[c*27+(dz+1)*9+(dy+1)*3+(dx+1)], acc);
      }
    }
  }
  out[gid] = fb(acc);
}

// ---------------- final: x1 + lin + NCDHW-view gather of t2 -> f32 out ----------------
__global__ __launch_bounds__(256) void final_add(const u16* __restrict__ x1, const u16* __restrict__ lin,
                                                 const u16* __restrict__ t2, float* __restrict__ out){
  int gid = blockIdx.x*256 + threadIdx.x;
  int b  = gid / 4214784;
  int gg = gid - b*4214784;
  int ch = gg / LTOK;
  int sp = gg - ch*LTOK;
  out[gid] = bu(x1[gid]) + bu(lin[gid]) + bu(t2[((long)b*LTOK + sp)*192 + ch]);
}

extern "C" void kernel_launch(void* const* d_in, const int* in_sizes, int n_in,
                              void* d_out, int out_size, void* d_ws, size_t ws_size,
                              hipStream_t stream){
  const float* x      = (const float*)d_in[0];
  const float* n1g    = (const float*)d_in[2];
  const float* n1b    = (const float*)d_in[3];
  const float* qkv_w  = (const float*)d_in[4];
  const float* qkv_b  = (const float*)d_in[5];
  const float* rpb    = (const float*)d_in[6];
  const float* proj_w = (const float*)d_in[7];
  const float* proj_b = (const float*)d_in[8];
  const float* n2g    = (const float*)d_in[9];
  const float* n2b    = (const float*)d_in[10];
  const float* l1w    = (const float*)d_in[11];
  const float* l1b    = (const float*)d_in[12];
  const float* l2w    = (const float*)d_in[13];
  const float* l2b    = (const float*)d_in[14];
  const float* dw1k   = (const float*)d_in[15];
  const float* dw1b   = (const float*)d_in[16];
  const float* pw1k   = (const float*)d_in[17];
  const float* pw1b   = (const float*)d_in[18];
  const float* dw2k   = (const float*)d_in[19];
  const float* dw2b   = (const float*)d_in[20];
  const float* pw2k   = (const float*)d_in[21];
  const float* pw2b   = (const float*)d_in[22];

  const size_t FB = (size_t)ROWSZ * DIMC;
  u16* x1b   = (u16*)d_ws;
  u16* winb  = x1b + FB;
  u16* attnb = winb + FB;
  u16* qkvb  = attnb + FB;      // 3*FB
  u16* cb1   = qkvb;
  u16* cb2   = qkvb + FB;
  u16* xmb   = winb;
  u16* linb  = attnb;
  u16* pk_qkv  = x1b + 6*FB;
  u16* pk_proj = pk_qkv  + 110592;
  u16* pk_l1   = pk_proj + 36864;
  u16* pk_l2   = pk_l1   + 147456;
  u16* pk_pw1  = pk_l2   + 147456;
  u16* pk_pw2  = pk_pw1  + 36864;

  pack_w<0><<<432,256,0,stream>>>(qkv_w,  pk_qkv,  192, 576);
  pack_w<0><<<144,256,0,stream>>>(proj_w, pk_proj, 192, 192);
  pack_w<0><<<576,256,0,stream>>>(l1w,    pk_l1,   192, 768);
  pack_w<0><<<576,256,0,stream>>>(l2w,    pk_l2,   768, 192);
  pack_w<1><<<144,256,0,stream>>>(pw1k,   pk_pw1,  192, 192);
  pack_w<1><<<144,256,0,stream>>>(pw2k,   pk_pw2,  192, 192);

  ln_win<<<ROWSZ/4,256,0,stream>>>(x, n1g, n1b, winb);
  gemm_mfma<576,0><<<ROWSZ/32,256,0,stream>>>(winb, pk_qkv, qkv_b, qkvb, nullptr);
  attn_mfma<<<128*6,256,0,stream>>>(qkvb, rpb, attnb);
  gemm_mfma<192,1><<<ROWSZ/32,256,0,stream>>>(attnb, pk_proj, proj_b, x1b, x);
  ln_plain<<<ROWSZ/4,256,0,stream>>>(x1b, n2g, n2b, xmb);
  mlp_mfma<<<ROWSZ/32,256,0,stream>>>(xmb, pk_l1, l1b, pk_l2, l2b, linb);
  dw3<<<TOTE/256,256,0,stream>>>(xmb, dw1k, dw1b, cb1);
  gemm_mfma<192,0><<<ROWSZ/32,256,0,stream>>>(cb1, pk_pw1, pw1b, cb2, nullptr);
  dw3<<<TOTE/256,256,0,stream>>>(cb2, dw2k, dw2b, cb1);
  gemm_mfma<192,0><<<ROWSZ/32,256,0,stream>>>(cb1, pk_pw2, pw2b, cb2, nullptr);
  final_add<<<TOTE/256,256,0,stream>>>(x1b, linb, cb2, (float*)d_out);
}

// Round 9
// 453.106 us; speedup vs baseline: 5.6040x; 1.8037x over previous
//
#include <hip/hip_runtime.h>

typedef unsigned short u16;
typedef unsigned int   u32;

#define DIMC 192
#define NWIN 343
#define LTOK 21952
#define ROWSZ 43904            // B * L rows
#define TOTE 8429568           // ROWSZ * DIMC
#define QSCALE 0.17677669529663689f
#define EPSF 1e-5f

typedef __attribute__((ext_vector_type(8))) short bf16x8v;
typedef __attribute__((ext_vector_type(4))) float f32x4v;

__device__ __forceinline__ float bu(u16 v){ union{u32 u; float f;} x; x.u = ((u32)v)<<16; return x.f; }
__device__ __forceinline__ float lo16(u32 p){ union{u32 u; float f;} x; x.u = p<<16; return x.f; }
__device__ __forceinline__ float hi16(u32 p){ union{u32 u; float f;} x; x.u = p & 0xffff0000u; return x.f; }
__device__ __forceinline__ u16 fb(float f){
  union{float ff; u32 u;} x; x.ff = f;
  u32 r = (x.u + 0x7fffu + ((x.u>>16)&1u)) >> 16;
  return (u16)r;
}
__device__ __forceinline__ float gelu_f(float x){ return 0.5f*x*(1.0f + erff(x*0.70710678118654752f)); }

__device__ __forceinline__ f32x4v mfma_bf16(bf16x8v a, bf16x8v b, f32x4v c){
  return __builtin_amdgcn_mfma_f32_16x16x32_bf16(a, b, c, 0, 0, 0);
}

// windowed-row -> (batch, token) bijection (shift -3 + partition).
__device__ __forceinline__ void row_to_token(int row, int& b, int& l){
  int bw = row / NWIN, n = row % NWIN;
  b = bw >> 6; int wi = bw & 63;
  int sd = (wi>>4)*7      + n/49;
  int sh = ((wi>>2)&3)*7  + (n/7)%7;
  int sw = (wi&3)*7       + n%7;
  int d = sd+3; if(d>=28) d-=28;
  int h = sh+3; if(h>=28) h-=28;
  int w = sw+3; if(w>=28) w-=28;
  l = d*784 + h*28 + w;
}

// ---------------- weight pre-pack into B-fragment order (bf16) ----------------
template<int TR>
__global__ __launch_bounds__(256) void pack_w(const float* __restrict__ W, u16* __restrict__ dst,
                                              int K, int N){
  int gid = blockIdx.x*256 + threadIdx.x;
  if(gid >= K*N) return;
  int k = gid / N, n = gid - k*N;
  float v = TR ? W[(long)n*K + k] : W[(long)k*N + n];
  int nt = n >> 4, ks = k >> 5;
  int l  = (((k>>3)&3)<<4) | (n&15);
  int j  = k & 7;
  int KS = K >> 5;
  dst[((((nt*KS + ks)<<6) + l)<<3) + j] = fb(v);
}

// ---------------- depthwise weight transpose: [192][27] -> [27][192] ----------------
__global__ __launch_bounds__(256) void pack_dwk(const float* __restrict__ k1, const float* __restrict__ k2,
                                                float* __restrict__ d1, float* __restrict__ d2){
  int gid = blockIdx.x*256 + threadIdx.x;
  if(gid < 5184){
    int tap = gid/192, c = gid - tap*192;
    d1[gid] = k1[c*27 + tap];
    d2[gid] = k2[c*27 + tap];
  }
}

// ---------------- LN1: f32 x -> bf16 windowed ----------------
__global__ __launch_bounds__(256) void ln_win(const float* __restrict__ x, const float* __restrict__ g,
                                              const float* __restrict__ bb, u16* __restrict__ out){
  int row  = blockIdx.x*4 + (threadIdx.x>>6);
  int lane = threadIdx.x & 63;
  int b, l; row_to_token(row, b, l);
  const float* p = x + ((long)b*LTOK + l)*DIMC;
  float v0 = p[lane], v1 = p[lane+64], v2 = p[lane+128];
  float s = v0+v1+v2;
  #pragma unroll
  for(int m=1;m<64;m<<=1) s += __shfl_xor(s,m);
  float mean = s*(1.f/192.f);
  float d0=v0-mean, d1=v1-mean, d2=v2-mean;
  float q = d0*d0+d1*d1+d2*d2;
  #pragma unroll
  for(int m=1;m<64;m<<=1) q += __shfl_xor(q,m);
  float rstd = rsqrtf(q*(1.f/192.f)+EPSF);
  u16* o = out + (long)row*DIMC;
  o[lane]     = fb(d0*rstd*g[lane]     + bb[lane]);
  o[lane+64]  = fb(d1*rstd*g[lane+64]  + bb[lane+64]);
  o[lane+128] = fb(d2*rstd*g[lane+128] + bb[lane+128]);
}

// ---------------- LN2: bf16 x1 -> bf16 xm ----------------
__global__ __launch_bounds__(256) void ln_plain(const u16* __restrict__ in, const float* __restrict__ g,
                                                const float* __restrict__ bb, u16* __restrict__ out){
  int row  = blockIdx.x*4 + (threadIdx.x>>6);
  int lane = threadIdx.x & 63;
  const u16* p = in + (long)row*DIMC;
  float v0 = bu(p[lane]), v1 = bu(p[lane+64]), v2 = bu(p[lane+128]);
  float s = v0+v1+v2;
  #pragma unroll
  for(int m=1;m<64;m<<=1) s += __shfl_xor(s,m);
  float mean = s*(1.f/192.f);
  float d0=v0-mean, d1=v1-mean, d2=v2-mean;
  float q = d0*d0+d1*d1+d2*d2;
  #pragma unroll
  for(int m=1;m<64;m<<=1) q += __shfl_xor(q,m);
  float rstd = rsqrtf(q*(1.f/192.f)+EPSF);
  u16* o = out + (long)row*DIMC;
  o[lane]     = fb(d0*rstd*g[lane]     + bb[lane]);
  o[lane+64]  = fb(d1*rstd*g[lane+64]  + bb[lane+64]);
  o[lane+128] = fb(d2*rstd*g[lane+128] + bb[lane+128]);
}

// ---------------- MFMA GEMM: 32 rows/block, K=192, 4 waves ----------------
template<int NTOT, int EPI>
__global__ __launch_bounds__(256) void gemm_mfma(const u16* __restrict__ A, const u16* __restrict__ Wp,
                                                 const float* __restrict__ bias, u16* __restrict__ out,
                                                 const float* __restrict__ resid){
  constexpr int KS  = 6;
  constexpr int NPW = NTOT/64;
  __shared__ u16 As[32*192];
  const int tid = threadIdx.x;
  const int w = tid>>6, l = tid&63;
  const int lm = l&15, lh = l>>4;
  const long row0 = (long)blockIdx.x*32;

  {
    const uint4* src = (const uint4*)(A + row0*192);
    #pragma unroll
    for(int c=0;c<3;c++){
      int cz = tid + c*256;
      int row = cz/24;
      int byte = (cz*16) ^ ((row&7)<<4);
      *(uint4*)((char*)As + byte) = src[cz];
    }
  }
  __syncthreads();

  f32x4v acc[NPW][2];
  const f32x4v z4 = {0.f,0.f,0.f,0.f};
  #pragma unroll
  for(int i=0;i<NPW;i++){ acc[i][0]=z4; acc[i][1]=z4; }

  #pragma unroll
  for(int ks=0;ks<KS;ks++){
    bf16x8v a[2];
    #pragma unroll
    for(int mt=0;mt<2;mt++){
      int row = mt*16 + lm;
      int byte = (row*384 + ks*64 + lh*16) ^ ((row&7)<<4);
      a[mt] = *(const bf16x8v*)((const char*)As + byte);
    }
    #pragma unroll
    for(int i=0;i<NPW;i++){
      int nt = w*NPW + i;
      bf16x8v b = *(const bf16x8v*)(Wp + ((((nt*KS + ks)<<6) + l)<<3));
      acc[i][0] = mfma_bf16(a[0], b, acc[i][0]);
      acc[i][1] = mfma_bf16(a[1], b, acc[i][1]);
    }
  }

  #pragma unroll
  for(int i=0;i<NPW;i++){
    int n = (w*NPW + i)*16 + lm;
    float bv = bias[n];
    #pragma unroll
    for(int mt=0;mt<2;mt++){
      #pragma unroll
      for(int r=0;r<4;r++){
        long mrow = row0 + mt*16 + lh*4 + r;
        float v = acc[i][mt][r] + bv;
        if constexpr(EPI==0){
          out[mrow*NTOT + n] = fb(v);
        } else {
          int b_, lt; row_to_token((int)mrow, b_, lt);
          long li = ((long)b_*LTOK + lt)*DIMC + n;
          out[li] = fb(v + resid[li]);
        }
      }
    }
  }
}

// ---------------- fused MLP via MFMA: h (32x768 bf16) kept in LDS ----------------
__global__ __launch_bounds__(256) void mlp_mfma(const u16* __restrict__ xm, const u16* __restrict__ Wp1,
                                                const float* __restrict__ b1, const u16* __restrict__ Wp2,
                                                const float* __restrict__ b2, u16* __restrict__ out){
  __shared__ u16 As[32*192];
  __shared__ u16 Hs[32*768];
  const int tid = threadIdx.x;
  const int w = tid>>6, l = tid&63;
  const int lm = l&15, lh = l>>4;
  const long row0 = (long)blockIdx.x*32;

  {
    const uint4* src = (const uint4*)(xm + row0*192);
    #pragma unroll
    for(int c=0;c<3;c++){
      int cz = tid + c*256;
      int row = cz/24;
      int byte = (cz*16) ^ ((row&7)<<4);
      *(uint4*)((char*)As + byte) = src[cz];
    }
  }
  __syncthreads();

  const f32x4v z4 = {0.f,0.f,0.f,0.f};
  f32x4v acc1[12][2];
  #pragma unroll
  for(int i=0;i<12;i++){ acc1[i][0]=z4; acc1[i][1]=z4; }

  #pragma unroll
  for(int ks=0;ks<6;ks++){
    bf16x8v a[2];
    #pragma unroll
    for(int mt=0;mt<2;mt++){
      int row = mt*16 + lm;
      int byte = (row*384 + ks*64 + lh*16) ^ ((row&7)<<4);
      a[mt] = *(const bf16x8v*)((const char*)As + byte);
    }
    #pragma unroll
    for(int i=0;i<12;i++){
      int nt = w*12 + i;
      bf16x8v b = *(const bf16x8v*)(Wp1 + ((((nt*6 + ks)<<6) + l)<<3));
      acc1[i][0] = mfma_bf16(a[0], b, acc1[i][0]);
      acc1[i][1] = mfma_bf16(a[1], b, acc1[i][1]);
    }
  }

  #pragma unroll
  for(int i=0;i<12;i++){
    int n = (w*12 + i)*16 + lm;
    float bv = b1[n];
    #pragma unroll
    for(int mt=0;mt<2;mt++){
      #pragma unroll
      for(int r=0;r<4;r++){
        int mrow = mt*16 + lh*4 + r;
        float h = gelu_f(acc1[i][mt][r] + bv);
        int byte = (mrow*1536 + n*2) ^ ((mrow&7)<<4);
        *(u16*)((char*)Hs + byte) = fb(h);
      }
    }
  }
  __syncthreads();

  f32x4v acc2[3][2];
  #pragma unroll
  for(int i=0;i<3;i++){ acc2[i][0]=z4; acc2[i][1]=z4; }

  #pragma unroll 4
  for(int ks=0;ks<24;ks++){
    bf16x8v a[2];
    #pragma unroll
    for(int mt=0;mt<2;mt++){
      int row = mt*16 + lm;
      int byte = (row*1536 + ks*64 + lh*16) ^ ((row&7)<<4);
      a[mt] = *(const bf16x8v*)((const char*)Hs + byte);
    }
    #pragma unroll
    for(int i=0;i<3;i++){
      int nt = w*3 + i;
      bf16x8v b = *(const bf16x8v*)(Wp2 + ((((nt*24 + ks)<<6) + l)<<3));
      acc2[i][0] = mfma_bf16(a[0], b, acc2[i][0]);
      acc2[i][1] = mfma_bf16(a[1], b, acc2[i][1]);
    }
  }

  #pragma unroll
  for(int i=0;i<3;i++){
    int n = (w*3 + i)*16 + lm;
    float bv = b2[n];
    #pragma unroll
    for(int mt=0;mt<2;mt++){
      #pragma unroll
      for(int r=0;r<4;r++){
        long mrow = row0 + mt*16 + lh*4 + r;
        out[mrow*192 + n] = fb(acc2[i][mt][r] + bv);
      }
    }
  }
}

// ---------------- MFMA attention: one block per (window, head), 4 waves ----------------
__global__ __launch_bounds__(256) void attn_mfma(const u16* __restrict__ qkv, const float* __restrict__ rpb,
                                                 u16* __restrict__ out){
  __shared__ u16 Qs[352*32];
  __shared__ u16 Ks2[352*32];
  __shared__ u16 Vt[32*360];
  __shared__ u16 Ps[4][16*360];
  __shared__ float rpb_l[2197];
  __shared__ u16 reg_l[352];

  const int tid = threadIdx.x;
  const int bw = blockIdx.x / 6, hh = blockIdx.x % 6;
  const int wi = bw & 63;
  const long rowbase = (long)bw*NWIN;

  for(int i=tid;i<2197;i+=256) rpb_l[i] = rpb[i*6+hh];
  for(int i2=tid;i2<352;i2+=256){
    int rg = 0;
    if(i2 < 343){
      int sd = (wi>>4)*7      + i2/49;
      int sh = ((wi>>2)&3)*7  + (i2/7)%7;
      int sw = (wi&3)*7       + i2%7;
      int rd = sd<21?0:(sd<25?1:2);
      int rh = sh<21?0:(sh<25?1:2);
      int rw = sw<21?0:(sw<25?1:2);
      rg = rd*9+rh*3+rw;
    }
    reg_l[i2] = (u16)rg;
  }
  if(tid < 144){ ((u32*)Qs)[343*16 + tid] = 0; ((u32*)Ks2)[343*16 + tid] = 0; }
  for(int p2=tid;p2<288;p2+=256){
    int d = p2/9, j = 343 + p2%9; Vt[d*360 + j] = 0;
  }

  for(int p = tid; p < 343*16; p += 256){
    int j = p >> 4, dp = p & 15;
    const u32* src = (const u32*)(qkv + (rowbase + j)*576 + hh*32) + dp;
    ((u32*)Qs)[j*16 + dp]  = src[0];
    ((u32*)Ks2)[j*16 + dp] = src[96];
    u32 vv = src[192];
    Vt[(dp*2)*360 + j]   = (u16)(vv & 0xffffu);
    Vt[(dp*2+1)*360 + j] = (u16)(vv >> 16);
  }
  __syncthreads();

  const int w = tid>>6, l = tid&63;
  const int lm = l&15, lh = l>>4;
  u16* Pw = Ps[w];
  const f32x4v z4 = {0.f,0.f,0.f,0.f};

  for(int it = w; it < 22; it += 4){
    const int i0 = it*16;
    bf16x8v aq = *(const bf16x8v*)(Qs + (i0+lm)*32 + lh*8);
    f32x4v acc[22];
    #pragma unroll
    for(int jt=0;jt<22;jt++){
      bf16x8v bk = *(const bf16x8v*)(Ks2 + (jt*16+lm)*32 + lh*8);
      acc[jt] = mfma_bf16(aq, bk, z4);
    }

    int izr[4], iyr[4], ixr[4], irr[4];
    #pragma unroll
    for(int r=0;r<4;r++){
      int i = i0 + lh*4 + r; if(i>342) i=342;
      izr[r]=i/49; int rem=i-izr[r]*49; iyr[r]=rem/7; ixr[r]=rem-iyr[r]*7;
      irr[r]=reg_l[i];
    }
    #pragma unroll
    for(int jt=0;jt<22;jt++){
      int j = jt*16 + lm;
      int jc = j>342?342:j;
      int jz=jc/49; int rem=jc-jz*49; int jy=rem/7; int jx=rem-jy*7;
      int rj = reg_l[jc];
      bool jok = j<343;
      #pragma unroll
      for(int r=0;r<4;r++){
        float bias = rpb_l[(izr[r]-jz+6)*169 + (iyr[r]-jy+6)*13 + (ixr[r]-jx+6)];
        float v = acc[jt][r]*QSCALE + bias + ((irr[r]==rj)?0.f:-100.f);
        acc[jt][r] = jok ? v : -1e30f;
      }
    }

    float rinv[4];
    #pragma unroll
    for(int r=0;r<4;r++){
      float mx = acc[0][r];
      #pragma unroll
      for(int jt=1;jt<22;jt++) mx = fmaxf(mx, acc[jt][r]);
      #pragma unroll
      for(int m=1;m<16;m<<=1) mx = fmaxf(mx, __shfl_xor(mx, m));
      float sm = 0.f;
      #pragma unroll
      for(int jt=0;jt<22;jt++){ float e = __expf(acc[jt][r]-mx); acc[jt][r]=e; sm += e; }
      #pragma unroll
      for(int m=1;m<16;m<<=1) sm += __shfl_xor(sm, m);
      rinv[r] = 1.0f/sm;
    }

    #pragma unroll
    for(int jt=0;jt<22;jt++){
      int j = jt*16+lm;
      #pragma unroll
      for(int r=0;r<4;r++) Pw[(lh*4+r)*360 + j] = fb(acc[jt][r]);
    }

    f32x4v o0=z4, o1=z4;
    #pragma unroll
    for(int ks=0;ks<11;ks++){
      bf16x8v ap = *(const bf16x8v*)(Pw + lm*360 + ks*32 + lh*8);
      bf16x8v b0 = *(const bf16x8v*)(Vt + lm*360 + ks*32 + lh*8);
      bf16x8v b1 = *(const bf16x8v*)(Vt + (16+lm)*360 + ks*32 + lh*8);
      o0 = mfma_bf16(ap, b0, o0);
      o1 = mfma_bf16(ap, b1, o1);
    }

    #pragma unroll
    for(int r=0;r<4;r++){
      int i = i0 + lh*4 + r;
      if(i < 343){
        u16* po = out + (rowbase + i)*192 + hh*32;
        po[lm]    = fb(o0[r]*rinv[r]);
        po[16+lm] = fb(o1[r]*rinv[r]);
      }
    }
  }
}

// ---------------- depthwise 3x3x3 conv, NDHWC, vectorized 8 ch/thread ----------------
__global__ __launch_bounds__(256) void dw3v(const u16* __restrict__ in, const float* __restrict__ kwT,
                                            const float* __restrict__ bias, u16* __restrict__ out){
  __shared__ float wls[5184];     // [tap][192]
  const int tid = threadIdx.x;
  for(int i=tid;i<5184;i+=256) wls[i] = kwT[i];
  __syncthreads();

  int gid = blockIdx.x*256 + tid;
  int t  = gid / 24, c8 = gid - t*24;
  int b  = t / LTOK, s = t - b*LTOK;
  int z  = s / 784; int r2 = s - z*784; int y = r2/28; int x = r2 - y*28;
  const u16* base = in + (long)t*192 + c8*8;

  float acc[8];
  {
    const float4* bp = (const float4*)(bias + c8*8);
    float4 b0 = bp[0], b1 = bp[1];
    acc[0]=b0.x; acc[1]=b0.y; acc[2]=b0.z; acc[3]=b0.w;
    acc[4]=b1.x; acc[5]=b1.y; acc[6]=b1.z; acc[7]=b1.w;
  }

  #pragma unroll
  for(int dz=-1;dz<=1;dz++){
    int zz=z+dz; if((unsigned)zz>=28u) continue;
    #pragma unroll
    for(int dy=-1;dy<=1;dy++){
      int yy=y+dy; if((unsigned)yy>=28u) continue;
      #pragma unroll
      for(int dx=-1;dx<=1;dx++){
        int xx=x+dx; if((unsigned)xx>=28u) continue;
        int tap = (dz+1)*9+(dy+1)*3+(dx+1);
        uint4 v = *(const uint4*)(base + (long)(dz*784+dy*28+dx)*192);
        const float* wp = &wls[tap*192 + c8*8];
        float4 w0 = *(const float4*)wp;
        float4 w1 = *(const float4*)(wp+4);
        acc[0] = fmaf(lo16(v.x), w0.x, acc[0]);
        acc[1] = fmaf(hi16(v.x), w0.y, acc[1]);
        acc[2] = fmaf(lo16(v.y), w0.z, acc[2]);
        acc[3] = fmaf(hi16(v.y), w0.w, acc[3]);
        acc[4] = fmaf(lo16(v.z), w1.x, acc[4]);
        acc[5] = fmaf(hi16(v.z), w1.y, acc[5]);
        acc[6] = fmaf(lo16(v.w), w1.z, acc[6]);
        acc[7] = fmaf(hi16(v.w), w1.w, acc[7]);
      }
    }
  }

  uint4 o;
  o.x = ((u32)fb(acc[1])<<16) | fb(acc[0]);
  o.y = ((u32)fb(acc[3])<<16) | fb(acc[2]);
  o.z = ((u32)fb(acc[5])<<16) | fb(acc[4]);
  o.w = ((u32)fb(acc[7])<<16) | fb(acc[6]);
  *(uint4*)(out + (long)t*192 + c8*8) = o;
}

// ---------------- final: x1 + lin + NCDHW-view gather of t2 -> f32 out ----------------
__global__ __launch_bounds__(256) void final_add(const u16* __restrict__ x1, const u16* __restrict__ lin,
                                                 const u16* __restrict__ t2, float* __restrict__ out){
  int gid = blockIdx.x*256 + threadIdx.x;
  int b  = gid / 4214784;
  int gg = gid - b*4214784;
  int ch = gg / LTOK;
  int sp = gg - ch*LTOK;
  out[gid] = bu(x1[gid]) + bu(lin[gid]) + bu(t2[((long)b*LTOK + sp)*192 + ch]);
}

extern "C" void kernel_launch(void* const* d_in, const int* in_sizes, int n_in,
                              void* d_out, int out_size, void* d_ws, size_t ws_size,
                              hipStream_t stream){
  const float* x      = (const float*)d_in[0];
  const float* n1g    = (const float*)d_in[2];
  const float* n1b    = (const float*)d_in[3];
  const float* qkv_w  = (const float*)d_in[4];
  const float* qkv_b  = (const float*)d_in[5];
  const float* rpb    = (const float*)d_in[6];
  const float* proj_w = (const float*)d_in[7];
  const float* proj_b = (const float*)d_in[8];
  const float* n2g    = (const float*)d_in[9];
  const float* n2b    = (const float*)d_in[10];
  const float* l1w    = (const float*)d_in[11];
  const float* l1b    = (const float*)d_in[12];
  const float* l2w    = (const float*)d_in[13];
  const float* l2b    = (const float*)d_in[14];
  const float* dw1k   = (const float*)d_in[15];
  const float* dw1b   = (const float*)d_in[16];
  const float* pw1k   = (const float*)d_in[17];
  const float* pw1b   = (const float*)d_in[18];
  const float* dw2k   = (const float*)d_in[19];
  const float* dw2b   = (const float*)d_in[20];
  const float* pw2k   = (const float*)d_in[21];
  const float* pw2b   = (const float*)d_in[22];

  const size_t FB = (size_t)ROWSZ * DIMC;
  u16* x1b   = (u16*)d_ws;
  u16* winb  = x1b + FB;
  u16* attnb = winb + FB;
  u16* qkvb  = attnb + FB;      // 3*FB
  u16* cb1   = qkvb;
  u16* cb2   = qkvb + FB;
  u16* xmb   = winb;
  u16* linb  = attnb;
  u16* pk_qkv  = x1b + 6*FB;
  u16* pk_proj = pk_qkv  + 110592;
  u16* pk_l1   = pk_proj + 36864;
  u16* pk_l2   = pk_l1   + 147456;
  u16* pk_pw1  = pk_l2   + 147456;
  u16* pk_pw2  = pk_pw1  + 36864;
  float* kwT1  = (float*)(pk_pw2 + 36864);   // 5184 f32
  float* kwT2  = kwT1 + 5184;

  pack_w<0><<<432,256,0,stream>>>(qkv_w,  pk_qkv,  192, 576);
  pack_w<0><<<144,256,0,stream>>>(proj_w, pk_proj, 192, 192);
  pack_w<0><<<576,256,0,stream>>>(l1w,    pk_l1,   192, 768);
  pack_w<0><<<576,256,0,stream>>>(l2w,    pk_l2,   768, 192);
  pack_w<1><<<144,256,0,stream>>>(pw1k,   pk_pw1,  192, 192);
  pack_w<1><<<144,256,0,stream>>>(pw2k,   pk_pw2,  192, 192);
  pack_dwk<<<21,256,0,stream>>>(dw1k, dw2k, kwT1, kwT2);

  ln_win<<<ROWSZ/4,256,0,stream>>>(x, n1g, n1b, winb);
  gemm_mfma<576,0><<<ROWSZ/32,256,0,stream>>>(winb, pk_qkv, qkv_b, qkvb, nullptr);
  attn_mfma<<<128*6,256,0,stream>>>(qkvb, rpb, attnb);
  gemm_mfma<192,1><<<ROWSZ/32,256,0,stream>>>(attnb, pk_proj, proj_b, x1b, x);
  ln_plain<<<ROWSZ/4,256,0,stream>>>(x1b, n2g, n2b, xmb);
  mlp_mfma<<<ROWSZ/32,256,0,stream>>>(xmb, pk_l1, l1b, pk_l2, l2b, linb);
  dw3v<<<4116,256,0,stream>>>(xmb, kwT1, dw1b, cb1);
  gemm_mfma<192,0><<<ROWSZ/32,256,0,stream>>>(cb1, pk_pw1, pw1b, cb2, nullptr);
  dw3v<<<4116,256,0,stream>>>(cb2, kwT2, dw2b, cb1);
  gemm_mfma<192,0><<<ROWSZ/32,256,0,stream>>>(cb1, pk_pw2, pw2b, cb2, nullptr);
  final_add<<<TOTE/256,256,0,stream>>>(x1b, linb, cb2, (float*)d_out);
}

// Round 10
// 421.012 us; speedup vs baseline: 6.0312x; 1.0762x over previous
//
#include <hip/hip_runtime.h>

typedef unsigned short u16;
typedef unsigned int   u32;

#define DIMC 192
#define NWIN 343
#define LTOK 21952
#define ROWSZ 43904            // B * L rows
#define TOTE 8429568           // ROWSZ * DIMC
#define QSCALE 0.17677669529663689f
#define EPSF 1e-5f

typedef __attribute__((ext_vector_type(8))) short bf16x8v;
typedef __attribute__((ext_vector_type(4))) float f32x4v;

__device__ __forceinline__ float bu(u16 v){ union{u32 u; float f;} x; x.u = ((u32)v)<<16; return x.f; }
__device__ __forceinline__ float lo16(u32 p){ union{u32 u; float f;} x; x.u = p<<16; return x.f; }
__device__ __forceinline__ float hi16(u32 p){ union{u32 u; float f;} x; x.u = p & 0xffff0000u; return x.f; }
__device__ __forceinline__ u16 fb(float f){
  union{float ff; u32 u;} x; x.ff = f;
  u32 r = (x.u + 0x7fffu + ((x.u>>16)&1u)) >> 16;
  return (u16)r;
}
__device__ __forceinline__ float gelu_f(float x){ return 0.5f*x*(1.0f + erff(x*0.70710678118654752f)); }

__device__ __forceinline__ f32x4v mfma_bf16(bf16x8v a, bf16x8v b, f32x4v c){
  return __builtin_amdgcn_mfma_f32_16x16x32_bf16(a, b, c, 0, 0, 0);
}

// windowed-row -> (batch, token) bijection (shift -3 + partition).
__device__ __forceinline__ void row_to_token(int row, int& b, int& l){
  int bw = row / NWIN, n = row % NWIN;
  b = bw >> 6; int wi = bw & 63;
  int sd = (wi>>4)*7      + n/49;
  int sh = ((wi>>2)&3)*7  + (n/7)%7;
  int sw = (wi&3)*7       + n%7;
  int d = sd+3; if(d>=28) d-=28;
  int h = sh+3; if(h>=28) h-=28;
  int w = sw+3; if(w>=28) w-=28;
  l = d*784 + h*28 + w;
}

// ---------------- weight pre-pack into B-fragment order (bf16) ----------------
template<int TR>
__global__ __launch_bounds__(256) void pack_w(const float* __restrict__ W, u16* __restrict__ dst,
                                              int K, int N){
  int gid = blockIdx.x*256 + threadIdx.x;
  if(gid >= K*N) return;
  int k = gid / N, n = gid - k*N;
  float v = TR ? W[(long)n*K + k] : W[(long)k*N + n];
  int nt = n >> 4, ks = k >> 5;
  int l  = (((k>>3)&3)<<4) | (n&15);
  int j  = k & 7;
  int KS = K >> 5;
  dst[((((nt*KS + ks)<<6) + l)<<3) + j] = fb(v);
}

// ---------------- depthwise weight transpose: [192][27] -> [27][192] ----------------
__global__ __launch_bounds__(256) void pack_dwk(const float* __restrict__ k1, const float* __restrict__ k2,
                                                float* __restrict__ d1, float* __restrict__ d2){
  int gid = blockIdx.x*256 + threadIdx.x;
  if(gid < 5184){
    int tap = gid/192, c = gid - tap*192;
    d1[gid] = k1[c*27 + tap];
    d2[gid] = k2[c*27 + tap];
  }
}

// ---------------- LN1: f32 x -> bf16 windowed ----------------
__global__ __launch_bounds__(256) void ln_win(const float* __restrict__ x, const float* __restrict__ g,
                                              const float* __restrict__ bb, u16* __restrict__ out){
  int row  = blockIdx.x*4 + (threadIdx.x>>6);
  int lane = threadIdx.x & 63;
  int b, l; row_to_token(row, b, l);
  const float* p = x + ((long)b*LTOK + l)*DIMC;
  float v0 = p[lane], v1 = p[lane+64], v2 = p[lane+128];
  float s = v0+v1+v2;
  #pragma unroll
  for(int m=1;m<64;m<<=1) s += __shfl_xor(s,m);
  float mean = s*(1.f/192.f);
  float d0=v0-mean, d1=v1-mean, d2=v2-mean;
  float q = d0*d0+d1*d1+d2*d2;
  #pragma unroll
  for(int m=1;m<64;m<<=1) q += __shfl_xor(q,m);
  float rstd = rsqrtf(q*(1.f/192.f)+EPSF);
  u16* o = out + (long)row*DIMC;
  o[lane]     = fb(d0*rstd*g[lane]     + bb[lane]);
  o[lane+64]  = fb(d1*rstd*g[lane+64]  + bb[lane+64]);
  o[lane+128] = fb(d2*rstd*g[lane+128] + bb[lane+128]);
}

// ---------------- LN2: bf16 x1 -> bf16 xm ----------------
__global__ __launch_bounds__(256) void ln_plain(const u16* __restrict__ in, const float* __restrict__ g,
                                                const float* __restrict__ bb, u16* __restrict__ out){
  int row  = blockIdx.x*4 + (threadIdx.x>>6);
  int lane = threadIdx.x & 63;
  const u16* p = in + (long)row*DIMC;
  float v0 = bu(p[lane]), v1 = bu(p[lane+64]), v2 = bu(p[lane+128]);
  float s = v0+v1+v2;
  #pragma unroll
  for(int m=1;m<64;m<<=1) s += __shfl_xor(s,m);
  float mean = s*(1.f/192.f);
  float d0=v0-mean, d1=v1-mean, d2=v2-mean;
  float q = d0*d0+d1*d1+d2*d2;
  #pragma unroll
  for(int m=1;m<64;m<<=1) q += __shfl_xor(q,m);
  float rstd = rsqrtf(q*(1.f/192.f)+EPSF);
  u16* o = out + (long)row*DIMC;
  o[lane]     = fb(d0*rstd*g[lane]     + bb[lane]);
  o[lane+64]  = fb(d1*rstd*g[lane+64]  + bb[lane+64]);
  o[lane+128] = fb(d2*rstd*g[lane+128] + bb[lane+128]);
}

// ---------------- MFMA GEMM: 32 rows/block, K=192, 4 waves ----------------
// QS=1: pre-scale first 192 output columns by QSCALE (qkv: q scaled at source)
template<int NTOT, int EPI, int QS = 0>
__global__ __launch_bounds__(256) void gemm_mfma(const u16* __restrict__ A, const u16* __restrict__ Wp,
                                                 const float* __restrict__ bias, u16* __restrict__ out,
                                                 const float* __restrict__ resid){
  constexpr int KS  = 6;
  constexpr int NPW = NTOT/64;
  __shared__ u16 As[32*192];
  const int tid = threadIdx.x;
  const int w = tid>>6, l = tid&63;
  const int lm = l&15, lh = l>>4;
  const long row0 = (long)blockIdx.x*32;

  {
    const uint4* src = (const uint4*)(A + row0*192);
    #pragma unroll
    for(int c=0;c<3;c++){
      int cz = tid + c*256;
      int row = cz/24;
      int byte = (cz*16) ^ ((row&7)<<4);
      *(uint4*)((char*)As + byte) = src[cz];
    }
  }
  __syncthreads();

  f32x4v acc[NPW][2];
  const f32x4v z4 = {0.f,0.f,0.f,0.f};
  #pragma unroll
  for(int i=0;i<NPW;i++){ acc[i][0]=z4; acc[i][1]=z4; }

  #pragma unroll
  for(int ks=0;ks<KS;ks++){
    bf16x8v a[2];
    #pragma unroll
    for(int mt=0;mt<2;mt++){
      int row = mt*16 + lm;
      int byte = (row*384 + ks*64 + lh*16) ^ ((row&7)<<4);
      a[mt] = *(const bf16x8v*)((const char*)As + byte);
    }
    #pragma unroll
    for(int i=0;i<NPW;i++){
      int nt = w*NPW + i;
      bf16x8v b = *(const bf16x8v*)(Wp + ((((nt*KS + ks)<<6) + l)<<3));
      acc[i][0] = mfma_bf16(a[0], b, acc[i][0]);
      acc[i][1] = mfma_bf16(a[1], b, acc[i][1]);
    }
  }

  #pragma unroll
  for(int i=0;i<NPW;i++){
    int n = (w*NPW + i)*16 + lm;
    float bv = bias[n];
    #pragma unroll
    for(int mt=0;mt<2;mt++){
      #pragma unroll
      for(int r=0;r<4;r++){
        long mrow = row0 + mt*16 + lh*4 + r;
        float v = acc[i][mt][r] + bv;
        if constexpr(QS){ if(n < 192) v *= QSCALE; }
        if constexpr(EPI==0){
          out[mrow*NTOT + n] = fb(v);
        } else {
          int b_, lt; row_to_token((int)mrow, b_, lt);
          long li = ((long)b_*LTOK + lt)*DIMC + n;
          out[li] = fb(v + resid[li]);
        }
      }
    }
  }
}

// ---------------- fused MLP via MFMA: h (32x768 bf16) kept in LDS ----------------
__global__ __launch_bounds__(256) void mlp_mfma(const u16* __restrict__ xm, const u16* __restrict__ Wp1,
                                                const float* __restrict__ b1, const u16* __restrict__ Wp2,
                                                const float* __restrict__ b2, u16* __restrict__ out){
  __shared__ u16 As[32*192];
  __shared__ u16 Hs[32*768];
  const int tid = threadIdx.x;
  const int w = tid>>6, l = tid&63;
  const int lm = l&15, lh = l>>4;
  const long row0 = (long)blockIdx.x*32;

  {
    const uint4* src = (const uint4*)(xm + row0*192);
    #pragma unroll
    for(int c=0;c<3;c++){
      int cz = tid + c*256;
      int row = cz/24;
      int byte = (cz*16) ^ ((row&7)<<4);
      *(uint4*)((char*)As + byte) = src[cz];
    }
  }
  __syncthreads();

  const f32x4v z4 = {0.f,0.f,0.f,0.f};
  f32x4v acc1[12][2];
  #pragma unroll
  for(int i=0;i<12;i++){ acc1[i][0]=z4; acc1[i][1]=z4; }

  #pragma unroll
  for(int ks=0;ks<6;ks++){
    bf16x8v a[2];
    #pragma unroll
    for(int mt=0;mt<2;mt++){
      int row = mt*16 + lm;
      int byte = (row*384 + ks*64 + lh*16) ^ ((row&7)<<4);
      a[mt] = *(const bf16x8v*)((const char*)As + byte);
    }
    #pragma unroll
    for(int i=0;i<12;i++){
      int nt = w*12 + i;
      bf16x8v b = *(const bf16x8v*)(Wp1 + ((((nt*6 + ks)<<6) + l)<<3));
      acc1[i][0] = mfma_bf16(a[0], b, acc1[i][0]);
      acc1[i][1] = mfma_bf16(a[1], b, acc1[i][1]);
    }
  }

  #pragma unroll
  for(int i=0;i<12;i++){
    int n = (w*12 + i)*16 + lm;
    float bv = b1[n];
    #pragma unroll
    for(int mt=0;mt<2;mt++){
      #pragma unroll
      for(int r=0;r<4;r++){
        int mrow = mt*16 + lh*4 + r;
        float h = gelu_f(acc1[i][mt][r] + bv);
        int byte = (mrow*1536 + n*2) ^ ((mrow&7)<<4);
        *(u16*)((char*)Hs + byte) = fb(h);
      }
    }
  }
  __syncthreads();

  f32x4v acc2[3][2];
  #pragma unroll
  for(int i=0;i<3;i++){ acc2[i][0]=z4; acc2[i][1]=z4; }

  #pragma unroll 4
  for(int ks=0;ks<24;ks++){
    bf16x8v a[2];
    #pragma unroll
    for(int mt=0;mt<2;mt++){
      int row = mt*16 + lm;
      int byte = (row*1536 + ks*64 + lh*16) ^ ((row&7)<<4);
      a[mt] = *(const bf16x8v*)((const char*)Hs + byte);
    }
    #pragma unroll
    for(int i=0;i<3;i++){
      int nt = w*3 + i;
      bf16x8v b = *(const bf16x8v*)(Wp2 + ((((nt*24 + ks)<<6) + l)<<3));
      acc2[i][0] = mfma_bf16(a[0], b, acc2[i][0]);
      acc2[i][1] = mfma_bf16(a[1], b, acc2[i][1]);
    }
  }

  #pragma unroll
  for(int i=0;i<3;i++){
    int n = (w*3 + i)*16 + lm;
    float bv = b2[n];
    #pragma unroll
    for(int mt=0;mt<2;mt++){
      #pragma unroll
      for(int r=0;r<4;r++){
        long mrow = row0 + mt*16 + lh*4 + r;
        out[mrow*192 + n] = fb(acc2[i][mt][r] + bv);
      }
    }
  }
}

// ---------------- MFMA attention v2: one block per (window, head), 4 waves ----------------
// Q read from global per tile (used once); K in fragment-order LDS (contiguous
// wave reads); P staged per-wave in two k-phases; rpb bf16; mask from lin|reg table.
__global__ __launch_bounds__(256) void attn_mfma(const u16* __restrict__ qkv, const float* __restrict__ rpb,
                                                 u16* __restrict__ out){
  __shared__ u16 Kf[22*512];        // 22528 B  fragment-order K
  __shared__ u16 Vt[32*360];        // 23040 B  V transposed [d][j]
  __shared__ u16 Ps[4][16*200];     // 25600 B  per-wave P (two phases)
  __shared__ u16 rpb_l[2198];       //  4396 B  rpb[:,hh] as bf16
  __shared__ u32 lin_l[352];        //  1408 B  lin(z,y,x) | region<<16

  const int tid = threadIdx.x;
  const int bw = blockIdx.x / 6, hh = blockIdx.x % 6;
  const int wi = bw & 63;
  const long rowbase = (long)bw*NWIN;

  for(int i=tid;i<2197;i+=256) rpb_l[i] = fb(rpb[i*6+hh]);
  for(int i2=tid;i2<352;i2+=256){
    u32 v = 0x7FFF0000u;            // pad sentinel (never matches a region)
    if(i2 < 343){
      int jz = i2/49, jr = i2-jz*49, jy = jr/7, jx = jr-jy*7;
      int sd = (wi>>4)*7 + jz, sh2 = ((wi>>2)&3)*7 + jy, sw = (wi&3)*7 + jx;
      int rd = sd<21?0:(sd<25?1:2);
      int rh = sh2<21?0:(sh2<25?1:2);
      int rw = sw<21?0:(sw<25?1:2);
      v = (u32)(jz*169 + jy*13 + jx) | ((u32)(rd*9+rh*3+rw)<<16);
    }
    lin_l[i2] = v;
  }
  for(int p2=tid;p2<288;p2+=256){
    int d = p2/9, j = 343 + p2%9; Vt[d*360 + j] = 0;
  }

  for(int p = tid; p < 343*16; p += 256){
    int j = p >> 4, dp = p & 15;
    const u32* src = (const u32*)(qkv + (rowbase + j)*576 + hh*32) + dp;
    u32 kk = src[96];                 // K at +192 u16
    u32 vv = src[192];                // V at +384 u16
    ((u32*)Kf)[(j>>4)*256 + ((dp>>2)*16 + (j&15))*4 + (dp&3)] = kk;
    Vt[(dp*2)*360 + j]   = (u16)(vv & 0xffffu);
    Vt[(dp*2+1)*360 + j] = (u16)(vv >> 16);
  }
  __syncthreads();

  const int w = tid>>6, l = tid&63;
  const int lm = l&15, lh = l>>4;
  u16* Pw = Ps[w];
  const f32x4v z4 = {0.f,0.f,0.f,0.f};

  for(int it = w; it < 22; it += 4){
    const int i0 = it*16;
    // Q A-fragment straight from global (pre-scaled by QSCALE in qkv GEMM)
    bf16x8v aq = *(const bf16x8v*)(qkv + (rowbase + i0 + lm)*576 + hh*32 + lh*8);

    f32x4v acc[22];
    #pragma unroll
    for(int jt=0;jt<22;jt++){
      bf16x8v bk = *(const bf16x8v*)(Kf + jt*512 + l*8);
      acc[jt] = mfma_bf16(aq, bk, z4);
    }

    // bias + mask fold: idx = lin_i - lin_j + 1098; region compare for mask
    u32 li[4];
    #pragma unroll
    for(int r=0;r<4;r++){
      int i = i0 + lh*4 + r; if(i>342) i=342;
      li[r] = lin_l[i];
    }
    #pragma unroll
    for(int jt=0;jt<22;jt++){
      u32 lj = lin_l[jt*16 + lm];
      bool jok = (jt*16 + lm) < 343;
      int ljl = (int)(lj & 0xffffu); u32 ljr = lj >> 16;
      #pragma unroll
      for(int r=0;r<4;r++){
        int idx = (int)(li[r] & 0xffffu) - ljl + 1098;
        float v = acc[jt][r] + bu(rpb_l[idx]) + (((li[r]>>16)==ljr) ? 0.f : -100.f);
        acc[jt][r] = jok ? v : -1e30f;
      }
    }

    float rinv[4];
    #pragma unroll
    for(int r=0;r<4;r++){
      float mx = acc[0][r];
      #pragma unroll
      for(int jt=1;jt<22;jt++) mx = fmaxf(mx, acc[jt][r]);
      #pragma unroll
      for(int m=1;m<16;m<<=1) mx = fmaxf(mx, __shfl_xor(mx, m));
      float sm = 0.f;
      #pragma unroll
      for(int jt=0;jt<22;jt++){ float e = __expf(acc[jt][r]-mx); acc[jt][r]=e; sm += e; }
      #pragma unroll
      for(int m=1;m<16;m<<=1) sm += __shfl_xor(sm, m);
      rinv[r] = 1.0f/sm;
    }

    f32x4v o0=z4, o1=z4;
    // phase A: jt 0..11 (k 0..191), 6 MFMA k-steps
    #pragma unroll
    for(int jt=0;jt<12;jt++){
      int jl = jt*16 + lm;
      #pragma unroll
      for(int r=0;r<4;r++) Pw[(lh*4+r)*200 + jl] = fb(acc[jt][r]);
    }
    #pragma unroll
    for(int ks=0;ks<6;ks++){
      bf16x8v ap = *(const bf16x8v*)(Pw + lm*200 + ks*32 + lh*8);
      bf16x8v b0 = *(const bf16x8v*)(Vt + lm*360 + ks*32 + lh*8);
      bf16x8v b1 = *(const bf16x8v*)(Vt + (16+lm)*360 + ks*32 + lh*8);
      o0 = mfma_bf16(ap, b0, o0);
      o1 = mfma_bf16(ap, b1, o1);
    }
    // phase B: jt 12..21 (k 192..351), 5 MFMA k-steps
    #pragma unroll
    for(int jt=12;jt<22;jt++){
      int jl = jt*16 + lm - 192;
      #pragma unroll
      for(int r=0;r<4;r++) Pw[(lh*4+r)*200 + jl] = fb(acc[jt][r]);
    }
    #pragma unroll
    for(int ks=0;ks<5;ks++){
      bf16x8v ap = *(const bf16x8v*)(Pw + lm*200 + ks*32 + lh*8);
      bf16x8v b0 = *(const bf16x8v*)(Vt + lm*360 + 192 + ks*32 + lh*8);
      bf16x8v b1 = *(const bf16x8v*)(Vt + (16+lm)*360 + 192 + ks*32 + lh*8);
      o0 = mfma_bf16(ap, b0, o0);
      o1 = mfma_bf16(ap, b1, o1);
    }

    #pragma unroll
    for(int r=0;r<4;r++){
      int i = i0 + lh*4 + r;
      if(i < 343){
        u16* po = out + (rowbase + i)*192 + hh*32;
        po[lm]    = fb(o0[r]*rinv[r]);
        po[16+lm] = fb(o1[r]*rinv[r]);
      }
    }
  }
}

// ---------------- depthwise 3x3x3 conv, NDHWC, vectorized 8 ch/thread ----------------
__global__ __launch_bounds__(256) void dw3v(const u16* __restrict__ in, const float* __restrict__ kwT,
                                            const float* __restrict__ bias, u16* __restrict__ out){
  __shared__ float wls[5184];     // [tap][192]
  const int tid = threadIdx.x;
  for(int i=tid;i<5184;i+=256) wls[i] = kwT[i];
  __syncthreads();

  int gid = blockIdx.x*256 + tid;
  int t  = gid / 24, c8 = gid - t*24;
  int b  = t / LTOK, s = t - b*LTOK;
  int z  = s / 784; int r2 = s - z*784; int y = r2/28; int x = r2 - y*28;
  const u16* base = in + (long)t*192 + c8*8;

  float acc[8];
  {
    const float4* bp = (const float4*)(bias + c8*8);
    float4 b0 = bp[0], b1 = bp[1];
    acc[0]=b0.x; acc[1]=b0.y; acc[2]=b0.z; acc[3]=b0.w;
    acc[4]=b1.x; acc[5]=b1.y; acc[6]=b1.z; acc[7]=b1.w;
  }

  #pragma unroll
  for(int dz=-1;dz<=1;dz++){
    int zz=z+dz; if((unsigned)zz>=28u) continue;
    #pragma unroll
    for(int dy=-1;dy<=1;dy++){
      int yy=y+dy; if((unsigned)yy>=28u) continue;
      #pragma unroll
      for(int dx=-1;dx<=1;dx++){
        int xx=x+dx; if((unsigned)xx>=28u) continue;
        int tap = (dz+1)*9+(dy+1)*3+(dx+1);
        uint4 v = *(const uint4*)(base + (long)(dz*784+dy*28+dx)*192);
        const float* wp = &wls[tap*192 + c8*8];
        float4 w0 = *(const float4*)wp;
        float4 w1 = *(const float4*)(wp+4);
        acc[0] = fmaf(lo16(v.x), w0.x, acc[0]);
        acc[1] = fmaf(hi16(v.x), w0.y, acc[1]);
        acc[2] = fmaf(lo16(v.y), w0.z, acc[2]);
        acc[3] = fmaf(hi16(v.y), w0.w, acc[3]);
        acc[4] = fmaf(lo16(v.z), w1.x, acc[4]);
        acc[5] = fmaf(hi16(v.z), w1.y, acc[5]);
        acc[6] = fmaf(lo16(v.w), w1.z, acc[6]);
        acc[7] = fmaf(hi16(v.w), w1.w, acc[7]);
      }
    }
  }

  uint4 o;
  o.x = ((u32)fb(acc[1])<<16) | fb(acc[0]);
  o.y = ((u32)fb(acc[3])<<16) | fb(acc[2]);
  o.z = ((u32)fb(acc[5])<<16) | fb(acc[4]);
  o.w = ((u32)fb(acc[7])<<16) | fb(acc[6]);
  *(uint4*)(out + (long)t*192 + c8*8) = o;
}

// ---------------- final: x1 + lin + NCDHW-view gather of t2 -> f32 out ----------------
__global__ __launch_bounds__(256) void final_add(const u16* __restrict__ x1, const u16* __restrict__ lin,
                                                 const u16* __restrict__ t2, float* __restrict__ out){
  int gid = blockIdx.x*256 + threadIdx.x;
  int b  = gid / 4214784;
  int gg = gid - b*4214784;
  int ch = gg / LTOK;
  int sp = gg - ch*LTOK;
  out[gid] = bu(x1[gid]) + bu(lin[gid]) + bu(t2[((long)b*LTOK + sp)*192 + ch]);
}

extern "C" void kernel_launch(void* const* d_in, const int* in_sizes, int n_in,
                              void* d_out, int out_size, void* d_ws, size_t ws_size,
                              hipStream_t stream){
  const float* x      = (const float*)d_in[0];
  const float* n1g    = (const float*)d_in[2];
  const float* n1b    = (const float*)d_in[3];
  const float* qkv_w  = (const float*)d_in[4];
  const float* qkv_b  = (const float*)d_in[5];
  const float* rpb    = (const float*)d_in[6];
  const float* proj_w = (const float*)d_in[7];
  const float* proj_b = (const float*)d_in[8];
  const float* n2g    = (const float*)d_in[9];
  const float* n2b    = (const float*)d_in[10];
  const float* l1w    = (const float*)d_in[11];
  const float* l1b    = (const float*)d_in[12];
  const float* l2w    = (const float*)d_in[13];
  const float* l2b    = (const float*)d_in[14];
  const float* dw1k   = (const float*)d_in[15];
  const float* dw1b   = (const float*)d_in[16];
  const float* pw1k   = (const float*)d_in[17];
  const float* pw1b   = (const float*)d_in[18];
  const float* dw2k   = (const float*)d_in[19];
  const float* dw2b   = (const float*)d_in[20];
  const float* pw2k   = (const float*)d_in[21];
  const float* pw2b   = (const float*)d_in[22];

  const size_t FB = (size_t)ROWSZ * DIMC;
  u16* x1b   = (u16*)d_ws;
  u16* winb  = x1b + FB;
  u16* attnb = winb + FB;
  u16* qkvb  = attnb + FB;      // 3*FB
  u16* cb1   = qkvb;
  u16* cb2   = qkvb + FB;
  u16* xmb   = winb;
  u16* linb  = attnb;
  u16* pk_qkv  = x1b + 6*FB;
  u16* pk_proj = pk_qkv  + 110592;
  u16* pk_l1   = pk_proj + 36864;
  u16* pk_l2   = pk_l1   + 147456;
  u16* pk_pw1  = pk_l2   + 147456;
  u16* pk_pw2  = pk_pw1  + 36864;
  float* kwT1  = (float*)(pk_pw2 + 36864);   // 5184 f32
  float* kwT2  = kwT1 + 5184;

  pack_w<0><<<432,256,0,stream>>>(qkv_w,  pk_qkv,  192, 576);
  pack_w<0><<<144,256,0,stream>>>(proj_w, pk_proj, 192, 192);
  pack_w<0><<<576,256,0,stream>>>(l1w,    pk_l1,   192, 768);
  pack_w<0><<<576,256,0,stream>>>(l2w,    pk_l2,   768, 192);
  pack_w<1><<<144,256,0,stream>>>(pw1k,   pk_pw1,  192, 192);
  pack_w<1><<<144,256,0,stream>>>(pw2k,   pk_pw2,  192, 192);
  pack_dwk<<<21,256,0,stream>>>(dw1k, dw2k, kwT1, kwT2);

  ln_win<<<ROWSZ/4,256,0,stream>>>(x, n1g, n1b, winb);
  gemm_mfma<576,0,1><<<ROWSZ/32,256,0,stream>>>(winb, pk_qkv, qkv_b, qkvb, nullptr);
  attn_mfma<<<128*6,256,0,stream>>>(qkvb, rpb, attnb);
  gemm_mfma<192,1><<<ROWSZ/32,256,0,stream>>>(attnb, pk_proj, proj_b, x1b, x);
  ln_plain<<<ROWSZ/4,256,0,stream>>>(x1b, n2g, n2b, xmb);
  mlp_mfma<<<ROWSZ/32,256,0,stream>>>(xmb, pk_l1, l1b, pk_l2, l2b, linb);
  dw3v<<<4116,256,0,stream>>>(xmb, kwT1, dw1b, cb1);
  gemm_mfma<192,0><<<ROWSZ/32,256,0,stream>>>(cb1, pk_pw1, pw1b, cb2, nullptr);
  dw3v<<<4116,256,0,stream>>>(cb2, kwT2, dw2b, cb1);
  gemm_mfma<192,0><<<ROWSZ/32,256,0,stream>>>(cb1, pk_pw2, pw2b, cb2, nullptr);
  final_add<<<TOTE/256,256,0,stream>>>(x1b, linb, cb2, (float*)d_out);
}

// Round 13
// 410.630 us; speedup vs baseline: 6.1837x; 1.0253x over previous
//
#include <hip/hip_runtime.h>

typedef unsigned short u16;
typedef unsigned int   u32;

#define DIMC 192
#define NWIN 343
#define LTOK 21952
#define ROWSZ 43904            // B * L rows
#define TOTE 8429568           // ROWSZ * DIMC
#define QSCALE 0.17677669529663689f
#define EPSF 1e-5f

typedef __attribute__((ext_vector_type(8))) short bf16x8v;
typedef __attribute__((ext_vector_type(4))) float f32x4v;

__device__ __forceinline__ float bu(u16 v){ union{u32 u; float f;} x; x.u = ((u32)v)<<16; return x.f; }
__device__ __forceinline__ float lo16(u32 p){ union{u32 u; float f;} x; x.u = p<<16; return x.f; }
__device__ __forceinline__ float hi16(u32 p){ union{u32 u; float f;} x; x.u = p & 0xffff0000u; return x.f; }
__device__ __forceinline__ u16 fb(float f){
  union{float ff; u32 u;} x; x.ff = f;
  u32 r = (x.u + 0x7fffu + ((x.u>>16)&1u)) >> 16;
  return (u16)r;
}
__device__ __forceinline__ float gelu_f(float x){ return 0.5f*x*(1.0f + erff(x*0.70710678118654752f)); }

__device__ __forceinline__ f32x4v mfma_bf16(bf16x8v a, bf16x8v b, f32x4v c){
  return __builtin_amdgcn_mfma_f32_16x16x32_bf16(a, b, c, 0, 0, 0);
}

// windowed-row -> (batch, token) bijection (shift -3 + partition).
__device__ __forceinline__ void row_to_token(int row, int& b, int& l){
  int bw = row / NWIN, n = row % NWIN;
  b = bw >> 6; int wi = bw & 63;
  int sd = (wi>>4)*7      + n/49;
  int sh = ((wi>>2)&3)*7  + (n/7)%7;
  int sw = (wi&3)*7       + n%7;
  int d = sd+3; if(d>=28) d-=28;
  int h = sh+3; if(h>=28) h-=28;
  int w = sw+3; if(w>=28) w-=28;
  l = d*784 + h*28 + w;
}

// ---------------- weight pre-pack into B-fragment order (bf16) ----------------
template<int TR>
__global__ __launch_bounds__(256) void pack_w(const float* __restrict__ W, u16* __restrict__ dst,
                                              int K, int N){
  int gid = blockIdx.x*256 + threadIdx.x;
  if(gid >= K*N) return;
  int k = gid / N, n = gid - k*N;
  float v = TR ? W[(long)n*K + k] : W[(long)k*N + n];
  int nt = n >> 4, ks = k >> 5;
  int l  = (((k>>3)&3)<<4) | (n&15);
  int j  = k & 7;
  int KS = K >> 5;
  dst[((((nt*KS + ks)<<6) + l)<<3) + j] = fb(v);
}

// ---------------- depthwise weight transpose: [192][27] -> [27][192] ----------------
__global__ __launch_bounds__(256) void pack_dwk(const float* __restrict__ k1, const float* __restrict__ k2,
                                                float* __restrict__ d1, float* __restrict__ d2){
  int gid = blockIdx.x*256 + threadIdx.x;
  if(gid < 5184){
    int tap = gid/192, c = gid - tap*192;
    d1[gid] = k1[c*27 + tap];
    d2[gid] = k2[c*27 + tap];
  }
}

// ---------------- LN1: f32 x -> bf16 windowed ----------------
__global__ __launch_bounds__(256) void ln_win(const float* __restrict__ x, const float* __restrict__ g,
                                              const float* __restrict__ bb, u16* __restrict__ out){
  int row  = blockIdx.x*4 + (threadIdx.x>>6);
  int lane = threadIdx.x & 63;
  int b, l; row_to_token(row, b, l);
  const float* p = x + ((long)b*LTOK + l)*DIMC;
  float v0 = p[lane], v1 = p[lane+64], v2 = p[lane+128];
  float s = v0+v1+v2;
  #pragma unroll
  for(int m=1;m<64;m<<=1) s += __shfl_xor(s,m);
  float mean = s*(1.f/192.f);
  float d0=v0-mean, d1=v1-mean, d2=v2-mean;
  float q = d0*d0+d1*d1+d2*d2;
  #pragma unroll
  for(int m=1;m<64;m<<=1) q += __shfl_xor(q,m);
  float rstd = rsqrtf(q*(1.f/192.f)+EPSF);
  u16* o = out + (long)row*DIMC;
  o[lane]     = fb(d0*rstd*g[lane]     + bb[lane]);
  o[lane+64]  = fb(d1*rstd*g[lane+64]  + bb[lane+64]);
  o[lane+128] = fb(d2*rstd*g[lane+128] + bb[lane+128]);
}

// ---------------- LN2: bf16 x1 -> bf16 xm ----------------
__global__ __launch_bounds__(256) void ln_plain(const u16* __restrict__ in, const float* __restrict__ g,
                                                const float* __restrict__ bb, u16* __restrict__ out){
  int row  = blockIdx.x*4 + (threadIdx.x>>6);
  int lane = threadIdx.x & 63;
  const u16* p = in + (long)row*DIMC;
  float v0 = bu(p[lane]), v1 = bu(p[lane+64]), v2 = bu(p[lane+128]);
  float s = v0+v1+v2;
  #pragma unroll
  for(int m=1;m<64;m<<=1) s += __shfl_xor(s,m);
  float mean = s*(1.f/192.f);
  float d0=v0-mean, d1=v1-mean, d2=v2-mean;
  float q = d0*d0+d1*d1+d2*d2;
  #pragma unroll
  for(int m=1;m<64;m<<=1) q += __shfl_xor(q,m);
  float rstd = rsqrtf(q*(1.f/192.f)+EPSF);
  u16* o = out + (long)row*DIMC;
  o[lane]     = fb(d0*rstd*g[lane]     + bb[lane]);
  o[lane+64]  = fb(d1*rstd*g[lane+64]  + bb[lane+64]);
  o[lane+128] = fb(d2*rstd*g[lane+128] + bb[lane+128]);
}

// ---------------- MFMA GEMM: 32 rows/block, K=192, 4 waves ----------------
// QS=1: pre-scale first 192 output columns by QSCALE (qkv: q scaled at source)
template<int NTOT, int EPI, int QS = 0>
__global__ __launch_bounds__(256) void gemm_mfma(const u16* __restrict__ A, const u16* __restrict__ Wp,
                                                 const float* __restrict__ bias, u16* __restrict__ out,
                                                 const float* __restrict__ resid){
  constexpr int KS  = 6;
  constexpr int NPW = NTOT/64;
  __shared__ u16 As[32*192];
  const int tid = threadIdx.x;
  const int w = tid>>6, l = tid&63;
  const int lm = l&15, lh = l>>4;
  const long row0 = (long)blockIdx.x*32;

  {
    const uint4* src = (const uint4*)(A + row0*192);
    #pragma unroll
    for(int c=0;c<3;c++){
      int cz = tid + c*256;
      int row = cz/24;
      int byte = (cz*16) ^ ((row&7)<<4);
      *(uint4*)((char*)As + byte) = src[cz];
    }
  }
  __syncthreads();

  f32x4v acc[NPW][2];
  const f32x4v z4 = {0.f,0.f,0.f,0.f};
  #pragma unroll
  for(int i=0;i<NPW;i++){ acc[i][0]=z4; acc[i][1]=z4; }

  #pragma unroll
  for(int ks=0;ks<KS;ks++){
    bf16x8v a[2];
    #pragma unroll
    for(int mt=0;mt<2;mt++){
      int row = mt*16 + lm;
      int byte = (row*384 + ks*64 + lh*16) ^ ((row&7)<<4);
      a[mt] = *(const bf16x8v*)((const char*)As + byte);
    }
    #pragma unroll
    for(int i=0;i<NPW;i++){
      int nt = w*NPW + i;
      bf16x8v b = *(const bf16x8v*)(Wp + ((((nt*KS + ks)<<6) + l)<<3));
      acc[i][0] = mfma_bf16(a[0], b, acc[i][0]);
      acc[i][1] = mfma_bf16(a[1], b, acc[i][1]);
    }
  }

  #pragma unroll
  for(int i=0;i<NPW;i++){
    int n = (w*NPW + i)*16 + lm;
    float bv = bias[n];
    #pragma unroll
    for(int mt=0;mt<2;mt++){
      #pragma unroll
      for(int r=0;r<4;r++){
        long mrow = row0 + mt*16 + lh*4 + r;
        float v = acc[i][mt][r] + bv;
        if constexpr(QS){ if(n < 192) v *= QSCALE; }
        if constexpr(EPI==0){
          out[mrow*NTOT + n] = fb(v);
        } else {
          int b_, lt; row_to_token((int)mrow, b_, lt);
          long li = ((long)b_*LTOK + lt)*DIMC + n;
          out[li] = fb(v + resid[li]);
        }
      }
    }
  }
}

// ---------------- fused MLP via MFMA: h (32x768 bf16) kept in LDS ----------------
__global__ __launch_bounds__(256) void mlp_mfma(const u16* __restrict__ xm, const u16* __restrict__ Wp1,
                                                const float* __restrict__ b1, const u16* __restrict__ Wp2,
                                                const float* __restrict__ b2, u16* __restrict__ out){
  __shared__ u16 As[32*192];
  __shared__ u16 Hs[32*768];
  const int tid = threadIdx.x;
  const int w = tid>>6, l = tid&63;
  const int lm = l&15, lh = l>>4;
  const long row0 = (long)blockIdx.x*32;

  {
    const uint4* src = (const uint4*)(xm + row0*192);
    #pragma unroll
    for(int c=0;c<3;c++){
      int cz = tid + c*256;
      int row = cz/24;
      int byte = (cz*16) ^ ((row&7)<<4);
      *(uint4*)((char*)As + byte) = src[cz];
    }
  }
  __syncthreads();

  const f32x4v z4 = {0.f,0.f,0.f,0.f};
  f32x4v acc1[12][2];
  #pragma unroll
  for(int i=0;i<12;i++){ acc1[i][0]=z4; acc1[i][1]=z4; }

  #pragma unroll
  for(int ks=0;ks<6;ks++){
    bf16x8v a[2];
    #pragma unroll
    for(int mt=0;mt<2;mt++){
      int row = mt*16 + lm;
      int byte = (row*384 + ks*64 + lh*16) ^ ((row&7)<<4);
      a[mt] = *(const bf16x8v*)((const char*)As + byte);
    }
    #pragma unroll
    for(int i=0;i<12;i++){
      int nt = w*12 + i;
      bf16x8v b = *(const bf16x8v*)(Wp1 + ((((nt*6 + ks)<<6) + l)<<3));
      acc1[i][0] = mfma_bf16(a[0], b, acc1[i][0]);
      acc1[i][1] = mfma_bf16(a[1], b, acc1[i][1]);
    }
  }

  #pragma unroll
  for(int i=0;i<12;i++){
    int n = (w*12 + i)*16 + lm;
    float bv = b1[n];
    #pragma unroll
    for(int mt=0;mt<2;mt++){
      #pragma unroll
      for(int r=0;r<4;r++){
        int mrow = mt*16 + lh*4 + r;
        float h = gelu_f(acc1[i][mt][r] + bv);
        int byte = (mrow*1536 + n*2) ^ ((mrow&7)<<4);
        *(u16*)((char*)Hs + byte) = fb(h);
      }
    }
  }
  __syncthreads();

  f32x4v acc2[3][2];
  #pragma unroll
  for(int i=0;i<3;i++){ acc2[i][0]=z4; acc2[i][1]=z4; }

  #pragma unroll 4
  for(int ks=0;ks<24;ks++){
    bf16x8v a[2];
    #pragma unroll
    for(int mt=0;mt<2;mt++){
      int row = mt*16 + lm;
      int byte = (row*1536 + ks*64 + lh*16) ^ ((row&7)<<4);
      a[mt] = *(const bf16x8v*)((const char*)Hs + byte);
    }
    #pragma unroll
    for(int i=0;i<3;i++){
      int nt = w*3 + i;
      bf16x8v b = *(const bf16x8v*)(Wp2 + ((((nt*24 + ks)<<6) + l)<<3));
      acc2[i][0] = mfma_bf16(a[0], b, acc2[i][0]);
      acc2[i][1] = mfma_bf16(a[1], b, acc2[i][1]);
    }
  }

  #pragma unroll
  for(int i=0;i<3;i++){
    int n = (w*3 + i)*16 + lm;
    float bv = b2[n];
    #pragma unroll
    for(int mt=0;mt<2;mt++){
      #pragma unroll
      for(int r=0;r<4;r++){
        long mrow = row0 + mt*16 + lh*4 + r;
        out[mrow*192 + n] = fb(acc2[i][mt][r] + bv);
      }
    }
  }
}

// ---------------- MFMA attention v3' (conservative): no max-pass, no pad-select,
// folded rpb index; manual fb P-packing ----------------
__global__ __launch_bounds__(256) void attn_mfma(const u16* __restrict__ qkv, const float* __restrict__ rpb,
                                                 u16* __restrict__ out){
  __shared__ u16 Kf[22*512];        // fragment-order K
  __shared__ u16 Vt[32*360];        // V transposed [d][j]
  __shared__ u16 Ps[4][16*200];     // per-wave P (two phases)
  __shared__ u16 rpb_l[2198];       // rpb[:,hh] bf16
  __shared__ u32 lin_l[352];        // lin(z,y,x) | region<<16

  const int tid = threadIdx.x;
  const int bw = blockIdx.x / 6, hh = blockIdx.x % 6;
  const int wi = bw & 63;
  const long rowbase = (long)bw*NWIN;

  for(int i=tid;i<2197;i+=256) rpb_l[i] = fb(rpb[i*6+hh]);
  for(int i2=tid;i2<352;i2+=256){
    u32 v = 0x7FFF0000u;            // pad sentinel: lin=0, region never matches
    if(i2 < 343){
      int jz = i2/49, jr = i2-jz*49, jy = jr/7, jx = jr-jy*7;
      int sd = (wi>>4)*7 + jz, sh2 = ((wi>>2)&3)*7 + jy, sw = (wi&3)*7 + jx;
      int rd = sd<21?0:(sd<25?1:2);
      int rh = sh2<21?0:(sh2<25?1:2);
      int rw = sw<21?0:(sw<25?1:2);
      v = (u32)(jz*169 + jy*13 + jx) | ((u32)(rd*9+rh*3+rw)<<16);
    }
    lin_l[i2] = v;
  }
  for(int p2=tid;p2<288;p2+=256){
    int d = p2/9, j = 343 + p2%9; Vt[d*360 + j] = 0;
  }
  ((u32*)Kf)[21*256 + tid] = 0;     // zero jt=21 block (pad cols j=343..351)
  __syncthreads();

  for(int p = tid; p < 343*16; p += 256){
    int j = p >> 4, dp = p & 15;
    const u32* src = (const u32*)(qkv + (rowbase + j)*576 + hh*32) + dp;
    u32 kk = src[96];                 // K at +192 u16
    u32 vv = src[192];                // V at +384 u16
    ((u32*)Kf)[(j>>4)*256 + ((dp>>2)*16 + (j&15))*4 + (dp&3)] = kk;
    Vt[(dp*2)*360 + j]   = (u16)(vv & 0xffffu);
    Vt[(dp*2+1)*360 + j] = (u16)(vv >> 16);
  }
  __syncthreads();

  const int w = tid>>6, l = tid&63;
  const int lm = l&15, lh = l>>4;
  u16* Pw = Ps[w];
  const f32x4v z4 = {0.f,0.f,0.f,0.f};

  for(int it = w; it < 22; it += 4){
    const int i0 = it*16;
    bf16x8v aq = *(const bf16x8v*)(qkv + (rowbase + i0 + lm)*576 + hh*32 + lh*8);

    f32x4v acc[22];
    #pragma unroll
    for(int jt=0;jt<22;jt++){
      bf16x8v bk = *(const bf16x8v*)(Kf + jt*512 + l*8);
      acc[jt] = mfma_bf16(aq, bk, z4);
    }

    int lia[4]; u32 lir[4];
    #pragma unroll
    for(int r=0;r<4;r++){
      int i = i0 + lh*4 + r; if(i>342) i=342;   // clamp: pad rows use row 342's bias (discarded at store)
      u32 t = lin_l[i];
      lia[r] = (int)(t & 0xffffu) + 1098;
      lir[r] = t >> 16;
    }
    #pragma unroll
    for(int jt=0;jt<22;jt++){
      u32 lj = lin_l[jt*16 + lm];
      int ljl = (int)(lj & 0xffffu); u32 ljr = lj >> 16;
      #pragma unroll
      for(int r=0;r<4;r++){
        int idx = lia[r] - ljl;
        acc[jt][r] = acc[jt][r] + bu(rpb_l[idx]) + ((lir[r]==ljr) ? 0.f : -100.f);
      }
    }

    // softmax without max-pass (scores bounded ~|0.5|; masked -> exp ~ 0)
    float rinv[4];
    #pragma unroll
    for(int r=0;r<4;r++){
      float sm = 0.f;
      #pragma unroll
      for(int jt=0;jt<22;jt++){ float e = __expf(acc[jt][r]); acc[jt][r]=e; sm += e; }
      #pragma unroll
      for(int m=1;m<16;m<<=1) sm += __shfl_xor(sm, m);
      rinv[r] = 1.0f/sm;
    }

    f32x4v o0=z4, o1=z4;
    // phase A: jt 0..11 (k 0..191)
    #pragma unroll
    for(int jt=0;jt<12;jt++){
      int jl = jt*16 + lm;
      #pragma unroll
      for(int r=0;r<4;r++) Pw[(lh*4+r)*200 + jl] = fb(acc[jt][r]);
    }
    #pragma unroll
    for(int ks=0;ks<6;ks++){
      bf16x8v ap = *(const bf16x8v*)(Pw + lm*200 + ks*32 + lh*8);
      bf16x8v b0 = *(const bf16x8v*)(Vt + lm*360 + ks*32 + lh*8);
      bf16x8v b1 = *(const bf16x8v*)(Vt + (16+lm)*360 + ks*32 + lh*8);
      o0 = mfma_bf16(ap, b0, o0);
      o1 = mfma_bf16(ap, b1, o1);
    }
    // phase B: jt 12..21 (k 192..351)
    #pragma unroll
    for(int jt=12;jt<22;jt++){
      int jl = jt*16 + lm - 192;
      #pragma unroll
      for(int r=0;r<4;r++) Pw[(lh*4+r)*200 + jl] = fb(acc[jt][r]);
    }
    #pragma unroll
    for(int ks=0;ks<5;ks++){
      bf16x8v ap = *(const bf16x8v*)(Pw + lm*200 + ks*32 + lh*8);
      bf16x8v b0 = *(const bf16x8v*)(Vt + lm*360 + 192 + ks*32 + lh*8);
      bf16x8v b1 = *(const bf16x8v*)(Vt + (16+lm)*360 + 192 + ks*32 + lh*8);
      o0 = mfma_bf16(ap, b0, o0);
      o1 = mfma_bf16(ap, b1, o1);
    }

    #pragma unroll
    for(int r=0;r<4;r++){
      int i = i0 + lh*4 + r;
      if(i < 343){
        u16* po = out + (rowbase + i)*192 + hh*32;
        po[lm]    = fb(o0[r]*rinv[r]);
        po[16+lm] = fb(o1[r]*rinv[r]);
      }
    }
  }
}

// ---------------- depthwise 3x3x3 conv, NDHWC, vectorized 8 ch/thread ----------------
__global__ __launch_bounds__(256) void dw3v(const u16* __restrict__ in, const float* __restrict__ kwT,
                                            const float* __restrict__ bias, u16* __restrict__ out){
  __shared__ float wls[5184];     // [tap][192]
  const int tid = threadIdx.x;
  for(int i=tid;i<5184;i+=256) wls[i] = kwT[i];
  __syncthreads();

  int gid = blockIdx.x*256 + tid;
  int t  = gid / 24, c8 = gid - t*24;
  int b  = t / LTOK, s = t - b*LTOK;
  int z  = s / 784; int r2 = s - z*784; int y = r2/28; int x = r2 - y*28;
  const u16* base = in + (long)t*192 + c8*8;

  float acc[8];
  {
    const float4* bp = (const float4*)(bias + c8*8);
    float4 b0 = bp[0], b1 = bp[1];
    acc[0]=b0.x; acc[1]=b0.y; acc[2]=b0.z; acc[3]=b0.w;
    acc[4]=b1.x; acc[5]=b1.y; acc[6]=b1.z; acc[7]=b1.w;
  }

  #pragma unroll
  for(int dz=-1;dz<=1;dz++){
    int zz=z+dz; if((unsigned)zz>=28u) continue;
    #pragma unroll
    for(int dy=-1;dy<=1;dy++){
      int yy=y+dy; if((unsigned)yy>=28u) continue;
      #pragma unroll
      for(int dx=-1;dx<=1;dx++){
        int xx=x+dx; if((unsigned)xx>=28u) continue;
        int tap = (dz+1)*9+(dy+1)*3+(dx+1);
        uint4 v = *(const uint4*)(base + (long)(dz*784+dy*28+dx)*192);
        const float* wp = &wls[tap*192 + c8*8];
        float4 w0 = *(const float4*)wp;
        float4 w1 = *(const float4*)(wp+4);
        acc[0] = fmaf(lo16(v.x), w0.x, acc[0]);
        acc[1] = fmaf(hi16(v.x), w0.y, acc[1]);
        acc[2] = fmaf(lo16(v.y), w0.z, acc[2]);
        acc[3] = fmaf(hi16(v.y), w0.w, acc[3]);
        acc[4] = fmaf(lo16(v.z), w1.x, acc[4]);
        acc[5] = fmaf(hi16(v.z), w1.y, acc[5]);
        acc[6] = fmaf(lo16(v.w), w1.z, acc[6]);
        acc[7] = fmaf(hi16(v.w), w1.w, acc[7]);
      }
    }
  }

  uint4 o;
  o.x = ((u32)fb(acc[1])<<16) | fb(acc[0]);
  o.y = ((u32)fb(acc[3])<<16) | fb(acc[2]);
  o.z = ((u32)fb(acc[5])<<16) | fb(acc[4]);
  o.w = ((u32)fb(acc[7])<<16) | fb(acc[6]);
  *(uint4*)(out + (long)t*192 + c8*8) = o;
}

// ---------------- final: x1 + lin + NCDHW-view gather of t2 -> f32 out ----------------
__global__ __launch_bounds__(256) void final_add(const u16* __restrict__ x1, const u16* __restrict__ lin,
                                                 const u16* __restrict__ t2, float* __restrict__ out){
  int gid = blockIdx.x*256 + threadIdx.x;
  int b  = gid / 4214784;
  int gg = gid - b*4214784;
  int ch = gg / LTOK;
  int sp = gg - ch*LTOK;
  out[gid] = bu(x1[gid]) + bu(lin[gid]) + bu(t2[((long)b*LTOK + sp)*192 + ch]);
}

extern "C" void kernel_launch(void* const* d_in, const int* in_sizes, int n_in,
                              void* d_out, int out_size, void* d_ws, size_t ws_size,
                              hipStream_t stream){
  const float* x      = (const float*)d_in[0];
  const float* n1g    = (const float*)d_in[2];
  const float* n1b    = (const float*)d_in[3];
  const float* qkv_w  = (const float*)d_in[4];
  const float* qkv_b  = (const float*)d_in[5];
  const float* rpb    = (const float*)d_in[6];
  const float* proj_w = (const float*)d_in[7];
  const float* proj_b = (const float*)d_in[8];
  const float* n2g    = (const float*)d_in[9];
  const float* n2b    = (const float*)d_in[10];
  const float* l1w    = (const float*)d_in[11];
  const float* l1b    = (const float*)d_in[12];
  const float* l2w    = (const float*)d_in[13];
  const float* l2b    = (const float*)d_in[14];
  const float* dw1k   = (const float*)d_in[15];
  const float* dw1b   = (const float*)d_in[16];
  const float* pw1k   = (const float*)d_in[17];
  const float* pw1b   = (const float*)d_in[18];
  const float* dw2k   = (const float*)d_in[19];
  const float* dw2b   = (const float*)d_in[20];
  const float* pw2k   = (const float*)d_in[21];
  const float* pw2b   = (const float*)d_in[22];

  const size_t FB = (size_t)ROWSZ * DIMC;
  u16* x1b   = (u16*)d_ws;
  u16* winb  = x1b + FB;
  u16* attnb = winb + FB;
  u16* qkvb  = attnb + FB;      // 3*FB
  u16* cb1   = qkvb;
  u16* cb2   = qkvb + FB;
  u16* xmb   = winb;
  u16* linb  = attnb;
  u16* pk_qkv  = x1b + 6*FB;
  u16* pk_proj = pk_qkv  + 110592;
  u16* pk_l1   = pk_proj + 36864;
  u16* pk_l2   = pk_l1   + 147456;
  u16* pk_pw1  = pk_l2   + 147456;
  u16* pk_pw2  = pk_pw1  + 36864;
  float* kwT1  = (float*)(pk_pw2 + 36864);   // 5184 f32
  float* kwT2  = kwT1 + 5184;

  pack_w<0><<<432,256,0,stream>>>(qkv_w,  pk_qkv,  192, 576);
  pack_w<0><<<144,256,0,stream>>>(proj_w, pk_proj, 192, 192);
  pack_w<0><<<576,256,0,stream>>>(l1w,    pk_l1,   192, 768);
  pack_w<0><<<576,256,0,stream>>>(l2w,    pk_l2,   768, 192);
  pack_w<1><<<144,256,0,stream>>>(pw1k,   pk_pw1,  192, 192);
  pack_w<1><<<144,256,0,stream>>>(pw2k,   pk_pw2,  192, 192);
  pack_dwk<<<21,256,0,stream>>>(dw1k, dw2k, kwT1, kwT2);

  ln_win<<<ROWSZ/4,256,0,stream>>>(x, n1g, n1b, winb);
  gemm_mfma<576,0,1><<<ROWSZ/32,256,0,stream>>>(winb, pk_qkv, qkv_b, qkvb, nullptr);
  attn_mfma<<<128*6,256,0,stream>>>(qkvb, rpb, attnb);
  gemm_mfma<192,1><<<ROWSZ/32,256,0,stream>>>(attnb, pk_proj, proj_b, x1b, x);
  ln_plain<<<ROWSZ/4,256,0,stream>>>(x1b, n2g, n2b, xmb);
  mlp_mfma<<<ROWSZ/32,256,0,stream>>>(xmb, pk_l1, l1b, pk_l2, l2b, linb);
  dw3v<<<4116,256,0,stream>>>(xmb, kwT1, dw1b, cb1);
  gemm_mfma<192,0><<<ROWSZ/32,256,0,stream>>>(cb1, pk_pw1, pw1b, cb2, nullptr);
  dw3v<<<4116,256,0,stream>>>(cb2, kwT2, dw2b, cb1);
  gemm_mfma<192,0><<<ROWSZ/32,256,0,stream>>>(cb1, pk_pw2, pw2b, cb2, nullptr);
  final_add<<<TOTE/256,256,0,stream>>>(x1b, linb, cb2, (float*)d_out);
}